// Round 19
// baseline (448.820 us; speedup 1.0000x reference)
//
#include <hip/hip_runtime.h>
#include <hip/hip_bf16.h>
#include <stdint.h>

// Problem constants
#define T_SEQ 2048
#define DM    2048
#define NH    16
#define NKVH  4
#define HD    128
#define NBATCH 4
#define BT    (NBATCH * T_SEQ)   // 8192 rows of x
#define ATT_SCALE 0.08838834764831845f  // 1/sqrt(128)
#define LOG2E 1.4426950408889634f

typedef __attribute__((ext_vector_type(8))) short bf16x8;
typedef __attribute__((ext_vector_type(4))) float f32x4;
typedef __attribute__((ext_vector_type(16))) float f32x16;
typedef __attribute__((ext_vector_type(8))) unsigned short ushort8;
typedef __attribute__((ext_vector_type(4))) unsigned short ushort4v;

static __device__ __forceinline__ unsigned short f2bf(float f) {
  __hip_bfloat16 h = __float2bfloat16(f);
  return __builtin_bit_cast(unsigned short, h);
}
static __device__ __forceinline__ float bf2f(unsigned short u) {
  unsigned int v = ((unsigned int)u) << 16;
  return __builtin_bit_cast(float, v);
}
static __device__ __forceinline__ unsigned int cvtpk(float a, float b) {
  unsigned int r;
  asm("v_cvt_pk_bf16_f32 %0, %1, %2" : "=v"(r) : "v"(a), "v"(b));
  return r;
}

#define GLDS16(g, l)                                                        \
  __builtin_amdgcn_global_load_lds(                                         \
      (const __attribute__((address_space(1))) void*)(g),                   \
      (__attribute__((address_space(3))) void*)(l), 16, 0, 0)

// ---------------------------------------------------------------- cast x
__global__ __launch_bounds__(256) void castx_k(const float* __restrict__ x,
                                               unsigned short* __restrict__ xb) {
  int i = (blockIdx.x * 256 + threadIdx.x) * 4;
  float4 v = *(const float4*)&x[i];
  ushort4v o;
  o[0] = f2bf(v.x); o[1] = f2bf(v.y); o[2] = f2bf(v.z); o[3] = f2bf(v.w);
  *(ushort4v*)&xb[i] = o;
}

// ------------------------------------------- cast + transpose weights
// Merged QKV variant: bx<32 -> Wq (2048 cols), 32..39 -> Wk, 40..47 -> Wv.
__global__ __launch_bounds__(256) void transqkv_k(const float* __restrict__ Wq,
                                                  const float* __restrict__ Wk,
                                                  const float* __restrict__ Wv,
                                                  unsigned short* __restrict__ wqt) {
  __shared__ unsigned short t[64][72];
  const int bx = blockIdx.x;
  const float* src;
  unsigned short* dst;
  int ncols, n0;
  if (bx < 32) {
    src = Wq; dst = wqt; ncols = 2048; n0 = bx * 64;
  } else if (bx < 40) {
    src = Wk; dst = wqt + (size_t)2048 * 2048; ncols = 512; n0 = (bx - 32) * 64;
  } else {
    src = Wv; dst = wqt + (size_t)2560 * 2048; ncols = 512; n0 = (bx - 40) * 64;
  }
  const int r0 = blockIdx.y * 64;
  const int tid = threadIdx.x;
  const int tx = tid & 15, ty = tid >> 4;
#pragma unroll
  for (int i = 0; i < 4; i++) {
    int r = ty * 4 + i;
    float4 v = *(const float4*)&src[(size_t)(r0 + r) * ncols + n0 + tx * 4];
    t[r][tx * 4 + 0] = f2bf(v.x);
    t[r][tx * 4 + 1] = f2bf(v.y);
    t[r][tx * 4 + 2] = f2bf(v.z);
    t[r][tx * 4 + 3] = f2bf(v.w);
  }
  __syncthreads();
  int nl = tid >> 2, seg = tid & 3;
  ushort8 o0, o1;
#pragma unroll
  for (int j = 0; j < 8; j++) {
    o0[j] = t[seg * 16 + j][nl];
    o1[j] = t[seg * 16 + 8 + j][nl];
  }
  size_t base = (size_t)(n0 + nl) * 2048 + r0 + seg * 16;
  *(ushort8*)&dst[base] = o0;
  *(ushort8*)&dst[base + 8] = o1;
}

// single-matrix transpose (Wo)
__global__ __launch_bounds__(256) void transw_k(const float* __restrict__ src,
                                                unsigned short* __restrict__ dst,
                                                int ncols) {
  __shared__ unsigned short t[64][72];
  int n0 = blockIdx.x * 64, r0 = blockIdx.y * 64;
  int tid = threadIdx.x;
  int tx = tid & 15, ty = tid >> 4;
#pragma unroll
  for (int i = 0; i < 4; i++) {
    int r = ty * 4 + i;
    float4 v = *(const float4*)&src[(size_t)(r0 + r) * ncols + n0 + tx * 4];
    t[r][tx * 4 + 0] = f2bf(v.x);
    t[r][tx * 4 + 1] = f2bf(v.y);
    t[r][tx * 4 + 2] = f2bf(v.z);
    t[r][tx * 4 + 3] = f2bf(v.w);
  }
  __syncthreads();
  int nl = tid >> 2, seg = tid & 3;
  ushort8 o0, o1;
#pragma unroll
  for (int j = 0; j < 8; j++) {
    o0[j] = t[seg * 16 + j][nl];
    o1[j] = t[seg * 16 + 8 + j][nl];
  }
  size_t base = (size_t)(n0 + nl) * 2048 + r0 + seg * 16;
  *(ushort8*)&dst[base] = o0;
  *(ushort8*)&dst[base + 8] = o1;
}

// ---------------------------------------------------------------- GEMM: 256x256x64,
// 4-phase interleave + 2D L2-chunked block->tile mapping (round 11, confirmed win)
template <int EPI, int NBY, int BYG>
__global__ __launch_bounds__(512) void gemm8_k(const unsigned short* __restrict__ A,
                                               const unsigned short* __restrict__ Bt,
                                               unsigned short* __restrict__ q_out,
                                               unsigned short* __restrict__ k_out,
                                               unsigned short* __restrict__ v_out,
                                               float* __restrict__ f_out) {
  __shared__ __align__(16) unsigned short smem[65536];  // 128 KB

  const int tid = threadIdx.x;
  const int lane = tid & 63, wid = tid >> 6;
  const int wm = wid >> 2, wn = wid & 3;
  const int lr = lane & 15, lq = lane >> 4;
  const int sw = ((lr >> 2) & 1) << 1;

  const int k8 = blockIdx.x & 7;
  const int l = blockIdx.x >> 3;
  const int gi = l / (4 * BYG);
  const int t4 = l % (4 * BYG);
  const int bx = k8 * 4 + (t4 & 3);
  const int by = gi * BYG + (t4 >> 2);
  const int row0 = bx * 256, n00 = by * 256;

  const int clog = (tid & 7) ^ (((tid >> 5) & 1) << 1);
  const unsigned short* Asrc = A + (size_t)row0 * 2048 + clog * 8;
  const unsigned short* Bsrc = Bt + (size_t)n00 * 2048 + clog * 8;

  auto stageA = [&](int buf, int h, int k0) {
#pragma unroll
    for (int c = 0; c < 2; c++) {
      const int rl = c * 128 + h * 64 + (tid >> 3);
      GLDS16(Asrc + (size_t)rl * 2048 + k0,
             &smem[buf * 32768 + (c * 128 + h * 64) * 64 + tid * 8]);
    }
  };
  auto stageB = [&](int buf, int h, int k0) {
#pragma unroll
    for (int c = 0; c < 2; c++) {
      const int pr = h * 128 + c * 64 + (tid >> 3);
      const int p = pr >> 5;
      const int lg = (p < 4) ? (2 * p) : (2 * (p - 4) + 1);
      const int logical = lg * 32 + (pr & 31);
      GLDS16(Bsrc + (size_t)logical * 2048 + k0,
             &smem[buf * 32768 + 16384 + (h * 128 + c * 64) * 64 + tid * 8]);
    }
  };

  auto ldA = [&](int buf, int rl, int kh) -> bf16x8 {
    return *(const bf16x8*)&smem[buf * 32768 + rl * 64 + (((kh << 2) + lq) ^ sw) * 8];
  };
  auto ldB = [&](int buf, int ni, int kh) -> bf16x8 {
    const int p = (ni < 2) ? wn : (4 + wn);
    const int pr = p * 32 + (ni & 1) * 16 + lr;
    return *(const bf16x8*)&smem[buf * 32768 + 16384 + pr * 64 +
                                 (((kh << 2) + lq) ^ sw) * 8];
  };

  f32x4 acc[8][4] = {};

  stageA(0, 0, 0);
  stageB(0, 0, 0);
  stageB(0, 1, 0);
  stageA(0, 1, 0);

  bf16x8 af[4][2], bfr[4][2];

#pragma unroll 1
  for (int t = 0; t < 32; ++t) {
    const int buf = t & 1, obuf = buf ^ 1;
    const bool nx = (t + 1 < 32);
    const int k0n = (t + 1) << 6;

    asm volatile("s_waitcnt vmcnt(4)" ::: "memory");
    asm volatile("s_barrier" ::: "memory");
#pragma unroll
    for (int m = 0; m < 4; m++)
#pragma unroll
      for (int kh = 0; kh < 2; kh++) af[m][kh] = ldA(buf, wm * 128 + m * 16 + lr, kh);
#pragma unroll
    for (int ni = 0; ni < 2; ni++)
#pragma unroll
      for (int kh = 0; kh < 2; kh++) bfr[ni][kh] = ldB(buf, ni, kh);
    if (nx) stageA(obuf, 0, k0n);
    __builtin_amdgcn_s_setprio(1);
#pragma unroll
    for (int m = 0; m < 4; m++)
#pragma unroll
      for (int ni = 0; ni < 2; ni++)
#pragma unroll
        for (int kh = 0; kh < 2; kh++)
          acc[m][ni] = __builtin_amdgcn_mfma_f32_16x16x32_bf16(af[m][kh], bfr[ni][kh],
                                                               acc[m][ni], 0, 0, 0);
    __builtin_amdgcn_s_setprio(0);

    if (nx) asm volatile("s_waitcnt vmcnt(4)" ::: "memory");
    else    asm volatile("s_waitcnt vmcnt(2)" ::: "memory");
    asm volatile("s_barrier" ::: "memory");
#pragma unroll
    for (int ni = 2; ni < 4; ni++)
#pragma unroll
      for (int kh = 0; kh < 2; kh++) bfr[ni][kh] = ldB(buf, ni, kh);
    if (nx) stageB(obuf, 0, k0n);
    __builtin_amdgcn_s_setprio(1);
#pragma unroll
    for (int m = 0; m < 4; m++)
#pragma unroll
      for (int ni = 2; ni < 4; ni++)
#pragma unroll
        for (int kh = 0; kh < 2; kh++)
          acc[m][ni] = __builtin_amdgcn_mfma_f32_16x16x32_bf16(af[m][kh], bfr[ni][kh],
                                                               acc[m][ni], 0, 0, 0);
    __builtin_amdgcn_s_setprio(0);

    if (nx) asm volatile("s_waitcnt vmcnt(4)" ::: "memory");
    else    asm volatile("s_waitcnt vmcnt(0)" ::: "memory");
    asm volatile("s_barrier" ::: "memory");
#pragma unroll
    for (int m = 0; m < 4; m++)
#pragma unroll
      for (int kh = 0; kh < 2; kh++)
        af[m][kh] = ldA(buf, wm * 128 + 64 + m * 16 + lr, kh);
    if (nx) stageB(obuf, 1, k0n);
    __builtin_amdgcn_s_setprio(1);
#pragma unroll
    for (int m = 0; m < 4; m++)
#pragma unroll
      for (int ni = 0; ni < 2; ni++)
#pragma unroll
        for (int kh = 0; kh < 2; kh++)
          acc[4 + m][ni] = __builtin_amdgcn_mfma_f32_16x16x32_bf16(
              af[m][kh], bfr[ni][kh], acc[4 + m][ni], 0, 0, 0);
    __builtin_amdgcn_s_setprio(0);

    asm volatile("s_barrier" ::: "memory");
    if (nx) stageA(obuf, 1, k0n);
    __builtin_amdgcn_s_setprio(1);
#pragma unroll
    for (int m = 0; m < 4; m++)
#pragma unroll
      for (int ni = 2; ni < 4; ni++)
#pragma unroll
        for (int kh = 0; kh < 2; kh++)
          acc[4 + m][ni] = __builtin_amdgcn_mfma_f32_16x16x32_bf16(
              af[m][kh], bfr[ni][kh], acc[4 + m][ni], 0, 0, 0);
    __builtin_amdgcn_s_setprio(0);
  }

  const int rbase = row0 + wm * 128;
  const int cbase = n00 + wn * 64;
#pragma unroll
  for (int mi = 0; mi < 8; mi++)
#pragma unroll
    for (int ni = 0; ni < 4; ni++)
#pragma unroll
      for (int r = 0; r < 4; r++) {
        int row = rbase + mi * 16 + lq * 4 + r;
        int col = cbase + ni * 16 + lr;
        float v = acc[mi][ni][r];
        if (EPI == 0) {
          if (col < 2048) {
            q_out[(size_t)row * 2048 + col] = f2bf(v);
          } else if (col < 2560) {
            k_out[(size_t)row * 512 + (col - 2048)] = f2bf(v);
          } else {
            int nv = col - 2560;
            int kvh = nv >> 7, d = nv & 127;
            int b = row >> 11, tt = row & 2047;
            v_out[((size_t)(b * NKVH + kvh) * HD + d) * T_SEQ + tt] = f2bf(v);
          }
        } else {
          f_out[(size_t)row * 2048 + col] = v;
        }
      }
}

// ---------------------------------------------------------------- RoPE tables
// Writes BOTH layouts: tab[t][i] (for ropek_k: lanes vary i -> coalesced) and
// tabt[i][t] (for attn_k: lanes vary t -> coalesced).
__global__ __launch_bounds__(256) void rope_tab_k(float2* __restrict__ tab,
                                                  float2* __restrict__ tabt) {
  int idx = blockIdx.x * 256 + threadIdx.x;
  int t = idx >> 6, i = idx & 63;
  float theta = exp2f(-(float)i * (13.287712379549449f / 64.0f));
  float s, c;
  sincosf((float)t * theta, &s, &c);
  float2 cs = make_float2(c, s);
  tab[(t << 6) + i] = cs;
  tabt[(i << 11) + t] = cs;
}

// K-only rope (Q rope is folded into attn's Q-fragment load)
__global__ __launch_bounds__(256) void ropek_k(unsigned short* __restrict__ kb,
                                               const float2* __restrict__ tab) {
  int idx = blockIdx.x * 256 + threadIdx.x;
  int i = idx & 63;
  int wi = idx >> 6;
  int kvh = wi & 3;
  int bt = wi >> 2;
  int t = bt & (T_SEQ - 1);
  unsigned short* p = kb + (size_t)bt * 512 + kvh * HD;
  float2 cs = tab[(t << 6) + i];
  float x1 = bf2f(p[i]), x2 = bf2f(p[i + 64]);
  p[i] = f2bf(x1 * cs.x - x2 * cs.y);
  p[i + 64] = f2bf(x1 * cs.y + x2 * cs.x);
}

// ---------------------------------------------------------------- flash attention
// Round-18 structure; Q-RoPE preamble now reads the TRANSPOSED table
// rtab_t[i][t] so consecutive lanes (varying t) hit contiguous addresses.
__global__ __launch_bounds__(256) void attn_k(const unsigned short* __restrict__ qb,
                                              const unsigned short* __restrict__ kb,
                                              const unsigned short* __restrict__ vt,
                                              const float2* __restrict__ rtabt,
                                              unsigned short* __restrict__ ao) {
  __shared__ __align__(16) unsigned short smem[24576];

  const int bid = blockIdx.x;
  const int j = 15 - (bid >> 6);
  const int g = (bid & 7) | (((bid >> 3) & 1) << 3);
  const int hh = (bid >> 4) & 3;
  const int b = g >> 2, kvh = g & 3;
  const int h = kvh * 4 + hh;

  const int tid = threadIdx.x;
  const int wid = tid >> 6, lane = tid & 63;
  const int l31 = lane & 31, lh = lane >> 5;
  const int xr = l31 & 7;
  const float slope2 = exp2f(-0.5f * (float)(h + 1)) * LOG2E;
  const float scale2 = ATT_SCALE * LOG2E;

  const int q0 = j * 128 + wid * 32;
  const int dt_w = j * 4 + wid;
  const int nt = j * 4 + 4;

  const int krow = tid >> 4;
  const int cgk = (tid & 15) ^ (krow & 7);
  const int vr = tid >> 3;
  const int cgv = (tid & 7) ^ (vr & 7);

  const unsigned short* khead = kb + (size_t)(b * T_SEQ) * 512 + kvh * 128;
  const unsigned short* vhead = vt + (size_t)(b * NKVH + kvh) * HD * T_SEQ;

  auto stage = [&](int slot, int tile) {
    const int k0 = tile * 32;
    unsigned short* base = &smem[slot * 8192];
    GLDS16(khead + (size_t)(k0 + krow) * 512 + cgk * 8, base + tid * 8);
    GLDS16(khead + (size_t)(k0 + 16 + krow) * 512 + cgk * 8, base + 2048 + tid * 8);
    GLDS16(vhead + (size_t)(((cgv >> 2) << 6) + vr) * T_SEQ + k0 + (cgv & 3) * 8,
           base + 4096 + tid * 8);
    GLDS16(vhead + (size_t)(((cgv >> 2) << 6) + 32 + vr) * T_SEQ + k0 + (cgv & 3) * 8,
           base + 6144 + tid * 8);
  };

  unsigned short (*ot)[32][136] = (unsigned short(*)[32][136])smem;

  // issue prologue staging first: HBM latency hides under Q load + rope
  stage(0, nt - 1);
  stage(1, nt - 2);

  const unsigned short* qrow =
      qb + ((size_t)(b * T_SEQ + q0 + l31)) * 2048 + h * HD + lh * 8;
  bf16x8 qf[8];
#pragma unroll
  for (int ds = 0; ds < 8; ds++) qf[ds] = *(const bf16x8*)&qrow[ds * 16];

  // in-register Q-RoPE: pair (i, i+64), i = ds*16 + lh*8 + e (ds<4).
  // rtabt is [i][2048 t]: lane-varying t is the fast axis -> coalesced.
  {
    const float2* rt = rtabt + ((size_t)(lh * 8) << 11) + (q0 + l31);
#pragma unroll
    for (int ds = 0; ds < 4; ds++)
#pragma unroll
      for (int e = 0; e < 8; e++) {
        float2 cs = rt[(size_t)(ds * 16 + e) << 11];
        float x1 = bf2f((unsigned short)qf[ds][e]);
        float x2 = bf2f((unsigned short)qf[ds + 4][e]);
        qf[ds][e] = (short)f2bf(x1 * cs.x - x2 * cs.y);
        qf[ds + 4][e] = (short)f2bf(x1 * cs.y + x2 * cs.x);
      }
  }

  f32x16 oacc[4] = {};
  float m2 = -1e30f, l_half = 0.f;
  const float arow = -slope2 * (float)(q0 + l31);

  float cr[16];
#pragma unroll
  for (int r = 0; r < 16; r++) {
    const int crow = (r & 3) + 8 * (r >> 2) + 4 * lh;
    cr[r] = fmaf(slope2, (float)crow, arow);
  }

#pragma unroll 1
  for (int it = 0; it < nt; ++it) {
    const int tt = nt - 1 - it;
    if (it == nt - 1) {
      asm volatile("s_waitcnt vmcnt(0)" ::: "memory");
    } else {
      asm volatile("s_waitcnt vmcnt(4)" ::: "memory");
    }
    asm volatile("s_barrier" ::: "memory");
    if (tt >= 2) stage((it + 2) % 3, tt - 2);

    if (tt <= dt_w) {
      const int slot = it % 3;
      const unsigned short* Kb = &smem[slot * 8192];
      const unsigned short* Vb = &smem[slot * 8192 + 4096];
      const int k0 = tt * 32;

      bf16x8 kf[8];
#pragma unroll
      for (int ds = 0; ds < 8; ds++)
        kf[ds] = *(const bf16x8*)&Kb[l31 * 128 + ((2 * ds + lh) ^ xr) * 8];

      __builtin_amdgcn_s_setprio(1);
      f32x16 sca = 0.f, scb = 0.f;
#pragma unroll
      for (int ds = 0; ds < 4; ds++)
        sca = __builtin_amdgcn_mfma_f32_32x32x16_bf16(kf[ds], qf[ds], sca, 0, 0, 0);
#pragma unroll
      for (int ds = 4; ds < 8; ds++)
        scb = __builtin_amdgcn_mfma_f32_32x32x16_bf16(kf[ds], qf[ds], scb, 0, 0, 0);
      __builtin_amdgcn_s_setprio(0);

      bf16x8 vf[4][2];
#pragma unroll
      for (int dt = 0; dt < 4; dt++)
#pragma unroll
        for (int ks = 0; ks < 2; ks++)
          vf[dt][ks] = *(const bf16x8*)&Vb[((dt & 1) * 32 + l31) * 64 +
                                           (((dt >> 1) * 4 + 2 * ks + lh) ^ xr) * 8];

      float s1[16];
#pragma unroll
      for (int r = 0; r < 16; r++) s1[r] = fmaf(sca[r] + scb[r], scale2, cr[r]);
      if (tt == dt_w) {
#pragma unroll
        for (int r = 0; r < 16; r++) {
          const int crow = (r & 3) + 8 * (r >> 2) + 4 * lh;
          if (crow > l31) s1[r] = -1e30f;
        }
      }

      float z = fmaf(slope2, (float)k0, -m2);

      float t8[8], t4[4];
#pragma unroll
      for (int i = 0; i < 8; i++) t8[i] = fmaxf(s1[i], s1[i + 8]);
#pragma unroll
      for (int i = 0; i < 4; i++) t4[i] = fmaxf(t8[i], t8[i + 4]);
      float mx = fmaxf(fmaxf(t4[0], t4[1]), fmaxf(t4[2], t4[3]));

      float pr[16];
#pragma unroll
      for (int r = 0; r < 16; r++) pr[r] = exp2f(s1[r] + z);

      mx = fmaxf(mx, __shfl_xor(mx, 32));
      if (__any(mx + z > 8.f)) {
        const float mt = (mx + z) + m2;
        const float mnew = fmaxf(m2, mt);
        const float corr = exp2f(m2 - mnew);
        l_half *= corr;
#pragma unroll
        for (int dt = 0; dt < 4; dt++) oacc[dt] *= corr;
        m2 = mnew;
        z = fmaf(slope2, (float)k0, -m2);
#pragma unroll
        for (int r = 0; r < 16; r++) pr[r] = exp2f(s1[r] + z);
      }

      float a8[8], a4[4];
#pragma unroll
      for (int i = 0; i < 8; i++) a8[i] = pr[i] + pr[i + 8];
#pragma unroll
      for (int i = 0; i < 4; i++) a4[i] = a8[i] + a8[i + 4];
      l_half += (a4[0] + a4[1]) + (a4[2] + a4[3]);

      unsigned int w[8];
#pragma unroll
      for (int i = 0; i < 8; i++) w[i] = cvtpk(pr[2 * i], pr[2 * i + 1]);
      const unsigned int ta = __shfl_xor(lh ? w[0] : w[2], 32);
      const unsigned int tb = __shfl_xor(lh ? w[1] : w[3], 32);
      const unsigned int tc = __shfl_xor(lh ? w[4] : w[6], 32);
      const unsigned int td = __shfl_xor(lh ? w[5] : w[7], 32);
      union U4 { unsigned int u[4]; bf16x8 v; } f0, f1;
      f0.u[0] = lh ? ta : w[0];
      f0.u[1] = lh ? tb : w[1];
      f0.u[2] = lh ? w[2] : ta;
      f0.u[3] = lh ? w[3] : tb;
      f1.u[0] = lh ? tc : w[4];
      f1.u[1] = lh ? td : w[5];
      f1.u[2] = lh ? w[6] : tc;
      f1.u[3] = lh ? w[7] : td;

      __builtin_amdgcn_s_setprio(1);
#pragma unroll
      for (int dt = 0; dt < 4; dt++) {
        oacc[dt] =
            __builtin_amdgcn_mfma_f32_32x32x16_bf16(vf[dt][0], f0.v, oacc[dt], 0, 0, 0);
        oacc[dt] =
            __builtin_amdgcn_mfma_f32_32x32x16_bf16(vf[dt][1], f1.v, oacc[dt], 0, 0, 0);
      }
      __builtin_amdgcn_s_setprio(0);
    }
  }

  const float l_tot = l_half + __shfl_xor(l_half, 32);
  const float inv = 1.0f / l_tot;
  __syncthreads();
#pragma unroll
  for (int dt = 0; dt < 4; dt++)
#pragma unroll
    for (int rg = 0; rg < 4; rg++) {
      ushort4v o;
#pragma unroll
      for (int jj = 0; jj < 4; jj++) o[jj] = f2bf(oacc[dt][rg * 4 + jj] * inv);
      *(ushort4v*)&ot[wid][l31][dt * 32 + rg * 8 + lh * 4] = o;
    }
  __syncthreads();
  const int rrow = lane >> 4, chunk = lane & 15;
#pragma unroll
  for (int ps = 0; ps < 8; ps++) {
    const int row = ps * 4 + rrow;
    ushort8 v = *(const ushort8*)&ot[wid][row][chunk * 8];
    *(ushort8*)&ao[((size_t)(b * T_SEQ + q0 + row)) * 2048 + h * HD + chunk * 8] = v;
  }
}

// ---------------------------------------------------------------- launch
extern "C" void kernel_launch(void* const* d_in, const int* in_sizes, int n_in,
                              void* d_out, int out_size, void* d_ws, size_t ws_size,
                              hipStream_t stream) {
  const float* x = (const float*)d_in[0];
  const float* Wq = (const float*)d_in[1];
  const float* Wk = (const float*)d_in[2];
  const float* Wv = (const float*)d_in[3];
  const float* Wo = (const float*)d_in[4];

  char* w = (char*)d_ws;
  unsigned short* xb = (unsigned short*)w;                  // 33.5MB; attn out reuse
  unsigned short* wqt = (unsigned short*)(w + 33554432);    // 12.6MB; Wo^T reuse (first 8.4MB)
  unsigned short* qb = (unsigned short*)(w + 33554432 + 12582912);
  unsigned short* kb = (unsigned short*)(w + 33554432 + 12582912 + 33554432);
  unsigned short* vtb = (unsigned short*)(w + 33554432 + 12582912 + 33554432 + 8388608);
  // rope tables in the free tail of wqt (bytes 8.4..10.5MB): unused after
  // gemm0, disjoint from Wo^T (0..8.4MB).
  float2* rtab = (float2*)(w + 33554432 + 8388608);            // [t][i], 1MB
  float2* rtabt = (float2*)(w + 33554432 + 8388608 + 1048576); // [i][t], 1MB

  castx_k<<<16384, 256, 0, stream>>>(x, xb);
  transqkv_k<<<dim3(48, 32), 256, 0, stream>>>(Wq, Wk, Wv, wqt);
  gemm8_k<0, 12, 3><<<384, 512, 0, stream>>>(xb, wqt, qb, kb, vtb, nullptr);
  rope_tab_k<<<512, 256, 0, stream>>>(rtab, rtabt);
  ropek_k<<<8192, 256, 0, stream>>>(kb, rtab);
  transw_k<<<dim3(32, 32), 256, 0, stream>>>(Wo, wqt, 2048);
  attn_k<<<1024, 256, 0, stream>>>(qb, kb, vtb, rtabt, xb);
  gemm8_k<1, 8, 4><<<256, 512, 0, stream>>>(xb, wqt, nullptr, nullptr, nullptr,
                                            (float*)d_out);
}

// Round 20
// 443.448 us; speedup vs baseline: 1.0121x; 1.0121x over previous
//
#include <hip/hip_runtime.h>
#include <hip/hip_bf16.h>
#include <stdint.h>

// Problem constants
#define T_SEQ 2048
#define DM    2048
#define NH    16
#define NKVH  4
#define HD    128
#define NBATCH 4
#define BT    (NBATCH * T_SEQ)   // 8192 rows of x
#define ATT_SCALE 0.08838834764831845f  // 1/sqrt(128)
#define LOG2E 1.4426950408889634f

typedef __attribute__((ext_vector_type(8))) short bf16x8;
typedef __attribute__((ext_vector_type(4))) float f32x4;
typedef __attribute__((ext_vector_type(16))) float f32x16;
typedef __attribute__((ext_vector_type(8))) unsigned short ushort8;
typedef __attribute__((ext_vector_type(4))) unsigned short ushort4v;

static __device__ __forceinline__ unsigned short f2bf(float f) {
  __hip_bfloat16 h = __float2bfloat16(f);
  return __builtin_bit_cast(unsigned short, h);
}
static __device__ __forceinline__ float bf2f(unsigned short u) {
  unsigned int v = ((unsigned int)u) << 16;
  return __builtin_bit_cast(float, v);
}
static __device__ __forceinline__ unsigned int cvtpk(float a, float b) {
  unsigned int r;
  asm("v_cvt_pk_bf16_f32 %0, %1, %2" : "=v"(r) : "v"(a), "v"(b));
  return r;
}

#define GLDS16(g, l)                                                        \
  __builtin_amdgcn_global_load_lds(                                         \
      (const __attribute__((address_space(1))) void*)(g),                   \
      (__attribute__((address_space(3))) void*)(l), 16, 0, 0)

// ---------------------------------------------------------------- cast x
__global__ __launch_bounds__(256) void castx_k(const float* __restrict__ x,
                                               unsigned short* __restrict__ xb) {
  int i = (blockIdx.x * 256 + threadIdx.x) * 4;
  float4 v = *(const float4*)&x[i];
  ushort4v o;
  o[0] = f2bf(v.x); o[1] = f2bf(v.y); o[2] = f2bf(v.z); o[3] = f2bf(v.w);
  *(ushort4v*)&xb[i] = o;
}

// ------------------------------------------- cast + transpose weights
// Merged QKV variant: bx<32 -> Wq (2048 cols), 32..39 -> Wk, 40..47 -> Wv.
__global__ __launch_bounds__(256) void transqkv_k(const float* __restrict__ Wq,
                                                  const float* __restrict__ Wk,
                                                  const float* __restrict__ Wv,
                                                  unsigned short* __restrict__ wqt) {
  __shared__ unsigned short t[64][72];
  const int bx = blockIdx.x;
  const float* src;
  unsigned short* dst;
  int ncols, n0;
  if (bx < 32) {
    src = Wq; dst = wqt; ncols = 2048; n0 = bx * 64;
  } else if (bx < 40) {
    src = Wk; dst = wqt + (size_t)2048 * 2048; ncols = 512; n0 = (bx - 32) * 64;
  } else {
    src = Wv; dst = wqt + (size_t)2560 * 2048; ncols = 512; n0 = (bx - 40) * 64;
  }
  const int r0 = blockIdx.y * 64;
  const int tid = threadIdx.x;
  const int tx = tid & 15, ty = tid >> 4;
#pragma unroll
  for (int i = 0; i < 4; i++) {
    int r = ty * 4 + i;
    float4 v = *(const float4*)&src[(size_t)(r0 + r) * ncols + n0 + tx * 4];
    t[r][tx * 4 + 0] = f2bf(v.x);
    t[r][tx * 4 + 1] = f2bf(v.y);
    t[r][tx * 4 + 2] = f2bf(v.z);
    t[r][tx * 4 + 3] = f2bf(v.w);
  }
  __syncthreads();
  int nl = tid >> 2, seg = tid & 3;
  ushort8 o0, o1;
#pragma unroll
  for (int j = 0; j < 8; j++) {
    o0[j] = t[seg * 16 + j][nl];
    o1[j] = t[seg * 16 + 8 + j][nl];
  }
  size_t base = (size_t)(n0 + nl) * 2048 + r0 + seg * 16;
  *(ushort8*)&dst[base] = o0;
  *(ushort8*)&dst[base + 8] = o1;
}

// single-matrix transpose (Wo)
__global__ __launch_bounds__(256) void transw_k(const float* __restrict__ src,
                                                unsigned short* __restrict__ dst,
                                                int ncols) {
  __shared__ unsigned short t[64][72];
  int n0 = blockIdx.x * 64, r0 = blockIdx.y * 64;
  int tid = threadIdx.x;
  int tx = tid & 15, ty = tid >> 4;
#pragma unroll
  for (int i = 0; i < 4; i++) {
    int r = ty * 4 + i;
    float4 v = *(const float4*)&src[(size_t)(r0 + r) * ncols + n0 + tx * 4];
    t[r][tx * 4 + 0] = f2bf(v.x);
    t[r][tx * 4 + 1] = f2bf(v.y);
    t[r][tx * 4 + 2] = f2bf(v.z);
    t[r][tx * 4 + 3] = f2bf(v.w);
  }
  __syncthreads();
  int nl = tid >> 2, seg = tid & 3;
  ushort8 o0, o1;
#pragma unroll
  for (int j = 0; j < 8; j++) {
    o0[j] = t[seg * 16 + j][nl];
    o1[j] = t[seg * 16 + 8 + j][nl];
  }
  size_t base = (size_t)(n0 + nl) * 2048 + r0 + seg * 16;
  *(ushort8*)&dst[base] = o0;
  *(ushort8*)&dst[base + 8] = o1;
}

// ---------------------------------------------------------------- GEMM: 256x256x64,
// 4-phase interleave + 2D L2-chunked block->tile mapping (round 11, confirmed win)
template <int EPI, int NBY, int BYG>
__global__ __launch_bounds__(512) void gemm8_k(const unsigned short* __restrict__ A,
                                               const unsigned short* __restrict__ Bt,
                                               unsigned short* __restrict__ q_out,
                                               unsigned short* __restrict__ k_out,
                                               unsigned short* __restrict__ v_out,
                                               float* __restrict__ f_out) {
  __shared__ __align__(16) unsigned short smem[65536];  // 128 KB

  const int tid = threadIdx.x;
  const int lane = tid & 63, wid = tid >> 6;
  const int wm = wid >> 2, wn = wid & 3;
  const int lr = lane & 15, lq = lane >> 4;
  const int sw = ((lr >> 2) & 1) << 1;

  const int k8 = blockIdx.x & 7;
  const int l = blockIdx.x >> 3;
  const int gi = l / (4 * BYG);
  const int t4 = l % (4 * BYG);
  const int bx = k8 * 4 + (t4 & 3);
  const int by = gi * BYG + (t4 >> 2);
  const int row0 = bx * 256, n00 = by * 256;

  const int clog = (tid & 7) ^ (((tid >> 5) & 1) << 1);
  const unsigned short* Asrc = A + (size_t)row0 * 2048 + clog * 8;
  const unsigned short* Bsrc = Bt + (size_t)n00 * 2048 + clog * 8;

  auto stageA = [&](int buf, int h, int k0) {
#pragma unroll
    for (int c = 0; c < 2; c++) {
      const int rl = c * 128 + h * 64 + (tid >> 3);
      GLDS16(Asrc + (size_t)rl * 2048 + k0,
             &smem[buf * 32768 + (c * 128 + h * 64) * 64 + tid * 8]);
    }
  };
  auto stageB = [&](int buf, int h, int k0) {
#pragma unroll
    for (int c = 0; c < 2; c++) {
      const int pr = h * 128 + c * 64 + (tid >> 3);
      const int p = pr >> 5;
      const int lg = (p < 4) ? (2 * p) : (2 * (p - 4) + 1);
      const int logical = lg * 32 + (pr & 31);
      GLDS16(Bsrc + (size_t)logical * 2048 + k0,
             &smem[buf * 32768 + 16384 + (h * 128 + c * 64) * 64 + tid * 8]);
    }
  };

  auto ldA = [&](int buf, int rl, int kh) -> bf16x8 {
    return *(const bf16x8*)&smem[buf * 32768 + rl * 64 + (((kh << 2) + lq) ^ sw) * 8];
  };
  auto ldB = [&](int buf, int ni, int kh) -> bf16x8 {
    const int p = (ni < 2) ? wn : (4 + wn);
    const int pr = p * 32 + (ni & 1) * 16 + lr;
    return *(const bf16x8*)&smem[buf * 32768 + 16384 + pr * 64 +
                                 (((kh << 2) + lq) ^ sw) * 8];
  };

  f32x4 acc[8][4] = {};

  stageA(0, 0, 0);
  stageB(0, 0, 0);
  stageB(0, 1, 0);
  stageA(0, 1, 0);

  bf16x8 af[4][2], bfr[4][2];

#pragma unroll 1
  for (int t = 0; t < 32; ++t) {
    const int buf = t & 1, obuf = buf ^ 1;
    const bool nx = (t + 1 < 32);
    const int k0n = (t + 1) << 6;

    asm volatile("s_waitcnt vmcnt(4)" ::: "memory");
    asm volatile("s_barrier" ::: "memory");
#pragma unroll
    for (int m = 0; m < 4; m++)
#pragma unroll
      for (int kh = 0; kh < 2; kh++) af[m][kh] = ldA(buf, wm * 128 + m * 16 + lr, kh);
#pragma unroll
    for (int ni = 0; ni < 2; ni++)
#pragma unroll
      for (int kh = 0; kh < 2; kh++) bfr[ni][kh] = ldB(buf, ni, kh);
    if (nx) stageA(obuf, 0, k0n);
    __builtin_amdgcn_s_setprio(1);
#pragma unroll
    for (int m = 0; m < 4; m++)
#pragma unroll
      for (int ni = 0; ni < 2; ni++)
#pragma unroll
        for (int kh = 0; kh < 2; kh++)
          acc[m][ni] = __builtin_amdgcn_mfma_f32_16x16x32_bf16(af[m][kh], bfr[ni][kh],
                                                               acc[m][ni], 0, 0, 0);
    __builtin_amdgcn_s_setprio(0);

    if (nx) asm volatile("s_waitcnt vmcnt(4)" ::: "memory");
    else    asm volatile("s_waitcnt vmcnt(2)" ::: "memory");
    asm volatile("s_barrier" ::: "memory");
#pragma unroll
    for (int ni = 2; ni < 4; ni++)
#pragma unroll
      for (int kh = 0; kh < 2; kh++) bfr[ni][kh] = ldB(buf, ni, kh);
    if (nx) stageB(obuf, 0, k0n);
    __builtin_amdgcn_s_setprio(1);
#pragma unroll
    for (int m = 0; m < 4; m++)
#pragma unroll
      for (int ni = 2; ni < 4; ni++)
#pragma unroll
        for (int kh = 0; kh < 2; kh++)
          acc[m][ni] = __builtin_amdgcn_mfma_f32_16x16x32_bf16(af[m][kh], bfr[ni][kh],
                                                               acc[m][ni], 0, 0, 0);
    __builtin_amdgcn_s_setprio(0);

    if (nx) asm volatile("s_waitcnt vmcnt(4)" ::: "memory");
    else    asm volatile("s_waitcnt vmcnt(0)" ::: "memory");
    asm volatile("s_barrier" ::: "memory");
#pragma unroll
    for (int m = 0; m < 4; m++)
#pragma unroll
      for (int kh = 0; kh < 2; kh++)
        af[m][kh] = ldA(buf, wm * 128 + 64 + m * 16 + lr, kh);
    if (nx) stageB(obuf, 1, k0n);
    __builtin_amdgcn_s_setprio(1);
#pragma unroll
    for (int m = 0; m < 4; m++)
#pragma unroll
      for (int ni = 0; ni < 2; ni++)
#pragma unroll
        for (int kh = 0; kh < 2; kh++)
          acc[4 + m][ni] = __builtin_amdgcn_mfma_f32_16x16x32_bf16(
              af[m][kh], bfr[ni][kh], acc[4 + m][ni], 0, 0, 0);
    __builtin_amdgcn_s_setprio(0);

    asm volatile("s_barrier" ::: "memory");
    if (nx) stageA(obuf, 1, k0n);
    __builtin_amdgcn_s_setprio(1);
#pragma unroll
    for (int m = 0; m < 4; m++)
#pragma unroll
      for (int ni = 2; ni < 4; ni++)
#pragma unroll
        for (int kh = 0; kh < 2; kh++)
          acc[4 + m][ni] = __builtin_amdgcn_mfma_f32_16x16x32_bf16(
              af[m][kh], bfr[ni][kh], acc[4 + m][ni], 0, 0, 0);
    __builtin_amdgcn_s_setprio(0);
  }

  const int rbase = row0 + wm * 128;
  const int cbase = n00 + wn * 64;
#pragma unroll
  for (int mi = 0; mi < 8; mi++)
#pragma unroll
    for (int ni = 0; ni < 4; ni++)
#pragma unroll
      for (int r = 0; r < 4; r++) {
        int row = rbase + mi * 16 + lq * 4 + r;
        int col = cbase + ni * 16 + lr;
        float v = acc[mi][ni][r];
        if (EPI == 0) {
          if (col < 2048) {
            q_out[(size_t)row * 2048 + col] = f2bf(v);
          } else if (col < 2560) {
            k_out[(size_t)row * 512 + (col - 2048)] = f2bf(v);
          } else {
            int nv = col - 2560;
            int kvh = nv >> 7, d = nv & 127;
            int b = row >> 11, tt = row & 2047;
            v_out[((size_t)(b * NKVH + kvh) * HD + d) * T_SEQ + tt] = f2bf(v);
          }
        } else {
          f_out[(size_t)row * 2048 + col] = v;
        }
      }
}

// ---------------------------------------------------------------- RoPE table + K apply
__global__ __launch_bounds__(256) void rope_tab_k(float2* __restrict__ tab) {
  int idx = blockIdx.x * 256 + threadIdx.x;
  int t = idx >> 6, i = idx & 63;
  float theta = exp2f(-(float)i * (13.287712379549449f / 64.0f));
  float s, c;
  sincosf((float)t * theta, &s, &c);
  tab[idx] = make_float2(c, s);
}

// K-only rope (Q rope is folded into attn's Q-fragment load)
__global__ __launch_bounds__(256) void ropek_k(unsigned short* __restrict__ kb,
                                               const float2* __restrict__ tab) {
  int idx = blockIdx.x * 256 + threadIdx.x;
  int i = idx & 63;
  int wi = idx >> 6;
  int kvh = wi & 3;
  int bt = wi >> 2;
  int t = bt & (T_SEQ - 1);
  unsigned short* p = kb + (size_t)bt * 512 + kvh * HD;
  float2 cs = tab[(t << 6) + i];
  float x1 = bf2f(p[i]), x2 = bf2f(p[i + 64]);
  p[i] = f2bf(x1 * cs.x - x2 * cs.y);
  p[i + 64] = f2bf(x1 * cs.y + x2 * cs.x);
}

// ---------------------------------------------------------------- flash attention
// Round-14 verified loop body. Q-RoPE applied in-register at Q-fragment load
// (lane holds both rope-pair halves: d=ds*16+lh*8+e pairs with qf[ds+4][e];
// t mod 2048 = q0+l31 is lane-local). Prologue stages issued BEFORE the Q
// load+rope so HBM latency hides under the rope VALU.
__global__ __launch_bounds__(256) void attn_k(const unsigned short* __restrict__ qb,
                                              const unsigned short* __restrict__ kb,
                                              const unsigned short* __restrict__ vt,
                                              const float2* __restrict__ rtab,
                                              unsigned short* __restrict__ ao) {
  __shared__ __align__(16) unsigned short smem[24576];

  const int bid = blockIdx.x;
  const int j = 15 - (bid >> 6);
  const int g = (bid & 7) | (((bid >> 3) & 1) << 3);
  const int hh = (bid >> 4) & 3;
  const int b = g >> 2, kvh = g & 3;
  const int h = kvh * 4 + hh;

  const int tid = threadIdx.x;
  const int wid = tid >> 6, lane = tid & 63;
  const int l31 = lane & 31, lh = lane >> 5;
  const int xr = l31 & 7;
  const float slope2 = exp2f(-0.5f * (float)(h + 1)) * LOG2E;
  const float scale2 = ATT_SCALE * LOG2E;

  const int q0 = j * 128 + wid * 32;
  const int dt_w = j * 4 + wid;
  const int nt = j * 4 + 4;

  const int krow = tid >> 4;
  const int cgk = (tid & 15) ^ (krow & 7);
  const int vr = tid >> 3;
  const int cgv = (tid & 7) ^ (vr & 7);

  const unsigned short* khead = kb + (size_t)(b * T_SEQ) * 512 + kvh * 128;
  const unsigned short* vhead = vt + (size_t)(b * NKVH + kvh) * HD * T_SEQ;

  auto stage = [&](int slot, int tile) {
    const int k0 = tile * 32;
    unsigned short* base = &smem[slot * 8192];
    GLDS16(khead + (size_t)(k0 + krow) * 512 + cgk * 8, base + tid * 8);
    GLDS16(khead + (size_t)(k0 + 16 + krow) * 512 + cgk * 8, base + 2048 + tid * 8);
    GLDS16(vhead + (size_t)(((cgv >> 2) << 6) + vr) * T_SEQ + k0 + (cgv & 3) * 8,
           base + 4096 + tid * 8);
    GLDS16(vhead + (size_t)(((cgv >> 2) << 6) + 32 + vr) * T_SEQ + k0 + (cgv & 3) * 8,
           base + 6144 + tid * 8);
  };

  unsigned short (*ot)[32][136] = (unsigned short(*)[32][136])smem;

  // issue prologue staging first: HBM latency hides under Q load + rope
  stage(0, nt - 1);
  stage(1, nt - 2);

  const unsigned short* qrow =
      qb + ((size_t)(b * T_SEQ + q0 + l31)) * 2048 + h * HD + lh * 8;
  bf16x8 qf[8];
#pragma unroll
  for (int ds = 0; ds < 8; ds++) qf[ds] = *(const bf16x8*)&qrow[ds * 16];

  // in-register Q-RoPE: pair (i, i+64), i = ds*16 + lh*8 + e (ds<4)
  {
    const float2* rt = rtab + ((q0 + l31) << 6) + lh * 8;
#pragma unroll
    for (int ds = 0; ds < 4; ds++)
#pragma unroll
      for (int e = 0; e < 8; e++) {
        float2 cs = rt[ds * 16 + e];
        float x1 = bf2f((unsigned short)qf[ds][e]);
        float x2 = bf2f((unsigned short)qf[ds + 4][e]);
        qf[ds][e] = (short)f2bf(x1 * cs.x - x2 * cs.y);
        qf[ds + 4][e] = (short)f2bf(x1 * cs.y + x2 * cs.x);
      }
  }

  f32x16 oacc[4] = {};
  float m2 = -1e30f, l_half = 0.f;
  const float arow = -slope2 * (float)(q0 + l31);

  float cr[16];
#pragma unroll
  for (int r = 0; r < 16; r++) {
    const int crow = (r & 3) + 8 * (r >> 2) + 4 * lh;
    cr[r] = fmaf(slope2, (float)crow, arow);
  }

#pragma unroll 1
  for (int it = 0; it < nt; ++it) {
    const int tt = nt - 1 - it;
    if (it == nt - 1) {
      asm volatile("s_waitcnt vmcnt(0)" ::: "memory");
    } else {
      asm volatile("s_waitcnt vmcnt(4)" ::: "memory");
    }
    asm volatile("s_barrier" ::: "memory");
    if (tt >= 2) stage((it + 2) % 3, tt - 2);

    if (tt <= dt_w) {
      const int slot = it % 3;
      const unsigned short* Kb = &smem[slot * 8192];
      const unsigned short* Vb = &smem[slot * 8192 + 4096];
      const int k0 = tt * 32;

      bf16x8 kf[8];
#pragma unroll
      for (int ds = 0; ds < 8; ds++)
        kf[ds] = *(const bf16x8*)&Kb[l31 * 128 + ((2 * ds + lh) ^ xr) * 8];

      __builtin_amdgcn_s_setprio(1);
      f32x16 sca = 0.f, scb = 0.f;
#pragma unroll
      for (int ds = 0; ds < 4; ds++)
        sca = __builtin_amdgcn_mfma_f32_32x32x16_bf16(kf[ds], qf[ds], sca, 0, 0, 0);
#pragma unroll
      for (int ds = 4; ds < 8; ds++)
        scb = __builtin_amdgcn_mfma_f32_32x32x16_bf16(kf[ds], qf[ds], scb, 0, 0, 0);
      __builtin_amdgcn_s_setprio(0);

      bf16x8 vf[4][2];
#pragma unroll
      for (int dt = 0; dt < 4; dt++)
#pragma unroll
        for (int ks = 0; ks < 2; ks++)
          vf[dt][ks] = *(const bf16x8*)&Vb[((dt & 1) * 32 + l31) * 64 +
                                           (((dt >> 1) * 4 + 2 * ks + lh) ^ xr) * 8];

      float s1[16];
#pragma unroll
      for (int r = 0; r < 16; r++) s1[r] = fmaf(sca[r] + scb[r], scale2, cr[r]);
      if (tt == dt_w) {
#pragma unroll
        for (int r = 0; r < 16; r++) {
          const int crow = (r & 3) + 8 * (r >> 2) + 4 * lh;
          if (crow > l31) s1[r] = -1e30f;
        }
      }

      float z = fmaf(slope2, (float)k0, -m2);

      float t8[8], t4[4];
#pragma unroll
      for (int i = 0; i < 8; i++) t8[i] = fmaxf(s1[i], s1[i + 8]);
#pragma unroll
      for (int i = 0; i < 4; i++) t4[i] = fmaxf(t8[i], t8[i + 4]);
      float mx = fmaxf(fmaxf(t4[0], t4[1]), fmaxf(t4[2], t4[3]));

      float pr[16];
#pragma unroll
      for (int r = 0; r < 16; r++) pr[r] = exp2f(s1[r] + z);

      mx = fmaxf(mx, __shfl_xor(mx, 32));
      if (__any(mx + z > 8.f)) {
        const float mt = (mx + z) + m2;
        const float mnew = fmaxf(m2, mt);
        const float corr = exp2f(m2 - mnew);
        l_half *= corr;
#pragma unroll
        for (int dt = 0; dt < 4; dt++) oacc[dt] *= corr;
        m2 = mnew;
        z = fmaf(slope2, (float)k0, -m2);
#pragma unroll
        for (int r = 0; r < 16; r++) pr[r] = exp2f(s1[r] + z);
      }

      float a8[8], a4[4];
#pragma unroll
      for (int i = 0; i < 8; i++) a8[i] = pr[i] + pr[i + 8];
#pragma unroll
      for (int i = 0; i < 4; i++) a4[i] = a8[i] + a8[i + 4];
      l_half += (a4[0] + a4[1]) + (a4[2] + a4[3]);

      unsigned int w[8];
#pragma unroll
      for (int i = 0; i < 8; i++) w[i] = cvtpk(pr[2 * i], pr[2 * i + 1]);
      const unsigned int ta = __shfl_xor(lh ? w[0] : w[2], 32);
      const unsigned int tb = __shfl_xor(lh ? w[1] : w[3], 32);
      const unsigned int tc = __shfl_xor(lh ? w[4] : w[6], 32);
      const unsigned int td = __shfl_xor(lh ? w[5] : w[7], 32);
      union U4 { unsigned int u[4]; bf16x8 v; } f0, f1;
      f0.u[0] = lh ? ta : w[0];
      f0.u[1] = lh ? tb : w[1];
      f0.u[2] = lh ? w[2] : ta;
      f0.u[3] = lh ? w[3] : tb;
      f1.u[0] = lh ? tc : w[4];
      f1.u[1] = lh ? td : w[5];
      f1.u[2] = lh ? w[6] : tc;
      f1.u[3] = lh ? w[7] : td;

      __builtin_amdgcn_s_setprio(1);
#pragma unroll
      for (int dt = 0; dt < 4; dt++) {
        oacc[dt] =
            __builtin_amdgcn_mfma_f32_32x32x16_bf16(vf[dt][0], f0.v, oacc[dt], 0, 0, 0);
        oacc[dt] =
            __builtin_amdgcn_mfma_f32_32x32x16_bf16(vf[dt][1], f1.v, oacc[dt], 0, 0, 0);
      }
      __builtin_amdgcn_s_setprio(0);
    }
  }

  const float l_tot = l_half + __shfl_xor(l_half, 32);
  const float inv = 1.0f / l_tot;
  __syncthreads();
#pragma unroll
  for (int dt = 0; dt < 4; dt++)
#pragma unroll
    for (int rg = 0; rg < 4; rg++) {
      ushort4v o;
#pragma unroll
      for (int jj = 0; jj < 4; jj++) o[jj] = f2bf(oacc[dt][rg * 4 + jj] * inv);
      *(ushort4v*)&ot[wid][l31][dt * 32 + rg * 8 + lh * 4] = o;
    }
  __syncthreads();
  const int rrow = lane >> 4, chunk = lane & 15;
#pragma unroll
  for (int ps = 0; ps < 8; ps++) {
    const int row = ps * 4 + rrow;
    ushort8 v = *(const ushort8*)&ot[wid][row][chunk * 8];
    *(ushort8*)&ao[((size_t)(b * T_SEQ + q0 + row)) * 2048 + h * HD + chunk * 8] = v;
  }
}

// ---------------------------------------------------------------- launch
extern "C" void kernel_launch(void* const* d_in, const int* in_sizes, int n_in,
                              void* d_out, int out_size, void* d_ws, size_t ws_size,
                              hipStream_t stream) {
  const float* x = (const float*)d_in[0];
  const float* Wq = (const float*)d_in[1];
  const float* Wk = (const float*)d_in[2];
  const float* Wv = (const float*)d_in[3];
  const float* Wo = (const float*)d_in[4];

  char* w = (char*)d_ws;
  unsigned short* xb = (unsigned short*)w;                  // 33.5MB; attn out reuse
  unsigned short* wqt = (unsigned short*)(w + 33554432);    // 12.6MB; Wo^T reuse (first 8.4MB)
  unsigned short* qb = (unsigned short*)(w + 33554432 + 12582912);
  unsigned short* kb = (unsigned short*)(w + 33554432 + 12582912 + 33554432);
  unsigned short* vtb = (unsigned short*)(w + 33554432 + 12582912 + 33554432 + 8388608);
  // rtab (1MB) in the free tail of wqt (bytes 8.4..9.4MB): unused after gemm0,
  // disjoint from Wo^T (0..8.4MB) — and safe while attn reads it.
  float2* rtab = (float2*)(w + 33554432 + 8388608);

  castx_k<<<16384, 256, 0, stream>>>(x, xb);
  transqkv_k<<<dim3(48, 32), 256, 0, stream>>>(Wq, Wk, Wv, wqt);
  gemm8_k<0, 12, 3><<<384, 512, 0, stream>>>(xb, wqt, qb, kb, vtb, nullptr);
  rope_tab_k<<<512, 256, 0, stream>>>(rtab);
  ropek_k<<<8192, 256, 0, stream>>>(kb, rtab);
  transw_k<<<dim3(32, 32), 256, 0, stream>>>(Wo, wqt, 2048);
  attn_k<<<1024, 256, 0, stream>>>(qb, kb, vtb, rtab, xb);
  gemm8_k<1, 8, 4><<<256, 512, 0, stream>>>(xb, wqt, nullptr, nullptr, nullptr,
                                            (float*)d_out);
}

// Round 21
// 422.820 us; speedup vs baseline: 1.0615x; 1.0488x over previous
//
#include <hip/hip_runtime.h>
#include <hip/hip_bf16.h>
#include <stdint.h>

// Problem constants
#define T_SEQ 2048
#define DM    2048
#define NH    16
#define NKVH  4
#define HD    128
#define NBATCH 4
#define BT    (NBATCH * T_SEQ)   // 8192 rows of x
#define ATT_SCALE 0.08838834764831845f  // 1/sqrt(128)
#define LOG2E 1.4426950408889634f

typedef __attribute__((ext_vector_type(8))) short bf16x8;
typedef __attribute__((ext_vector_type(4))) float f32x4;
typedef __attribute__((ext_vector_type(16))) float f32x16;
typedef __attribute__((ext_vector_type(8))) unsigned short ushort8;
typedef __attribute__((ext_vector_type(4))) unsigned short ushort4v;

static __device__ __forceinline__ unsigned short f2bf(float f) {
  __hip_bfloat16 h = __float2bfloat16(f);
  return __builtin_bit_cast(unsigned short, h);
}
static __device__ __forceinline__ float bf2f(unsigned short u) {
  unsigned int v = ((unsigned int)u) << 16;
  return __builtin_bit_cast(float, v);
}
static __device__ __forceinline__ unsigned int cvtpk(float a, float b) {
  unsigned int r;
  asm("v_cvt_pk_bf16_f32 %0, %1, %2" : "=v"(r) : "v"(a), "v"(b));
  return r;
}

#define GLDS16(g, l)                                                        \
  __builtin_amdgcn_global_load_lds(                                         \
      (const __attribute__((address_space(1))) void*)(g),                   \
      (__attribute__((address_space(3))) void*)(l), 16, 0, 0)

// ---------------------------------------------------------------- cast x
__global__ __launch_bounds__(256) void castx_k(const float* __restrict__ x,
                                               unsigned short* __restrict__ xb) {
  int i = (blockIdx.x * 256 + threadIdx.x) * 4;
  float4 v = *(const float4*)&x[i];
  ushort4v o;
  o[0] = f2bf(v.x); o[1] = f2bf(v.y); o[2] = f2bf(v.z); o[3] = f2bf(v.w);
  *(ushort4v*)&xb[i] = o;
}

// ------------------------------------------- cast + transpose weights
// Merged QKV variant: bx<32 -> Wq (2048 cols), 32..39 -> Wk, 40..47 -> Wv.
__global__ __launch_bounds__(256) void transqkv_k(const float* __restrict__ Wq,
                                                  const float* __restrict__ Wk,
                                                  const float* __restrict__ Wv,
                                                  unsigned short* __restrict__ wqt) {
  __shared__ unsigned short t[64][72];
  const int bx = blockIdx.x;
  const float* src;
  unsigned short* dst;
  int ncols, n0;
  if (bx < 32) {
    src = Wq; dst = wqt; ncols = 2048; n0 = bx * 64;
  } else if (bx < 40) {
    src = Wk; dst = wqt + (size_t)2048 * 2048; ncols = 512; n0 = (bx - 32) * 64;
  } else {
    src = Wv; dst = wqt + (size_t)2560 * 2048; ncols = 512; n0 = (bx - 40) * 64;
  }
  const int r0 = blockIdx.y * 64;
  const int tid = threadIdx.x;
  const int tx = tid & 15, ty = tid >> 4;
#pragma unroll
  for (int i = 0; i < 4; i++) {
    int r = ty * 4 + i;
    float4 v = *(const float4*)&src[(size_t)(r0 + r) * ncols + n0 + tx * 4];
    t[r][tx * 4 + 0] = f2bf(v.x);
    t[r][tx * 4 + 1] = f2bf(v.y);
    t[r][tx * 4 + 2] = f2bf(v.z);
    t[r][tx * 4 + 3] = f2bf(v.w);
  }
  __syncthreads();
  int nl = tid >> 2, seg = tid & 3;
  ushort8 o0, o1;
#pragma unroll
  for (int j = 0; j < 8; j++) {
    o0[j] = t[seg * 16 + j][nl];
    o1[j] = t[seg * 16 + 8 + j][nl];
  }
  size_t base = (size_t)(n0 + nl) * 2048 + r0 + seg * 16;
  *(ushort8*)&dst[base] = o0;
  *(ushort8*)&dst[base + 8] = o1;
}

// single-matrix transpose (Wo)
__global__ __launch_bounds__(256) void transw_k(const float* __restrict__ src,
                                                unsigned short* __restrict__ dst,
                                                int ncols) {
  __shared__ unsigned short t[64][72];
  int n0 = blockIdx.x * 64, r0 = blockIdx.y * 64;
  int tid = threadIdx.x;
  int tx = tid & 15, ty = tid >> 4;
#pragma unroll
  for (int i = 0; i < 4; i++) {
    int r = ty * 4 + i;
    float4 v = *(const float4*)&src[(size_t)(r0 + r) * ncols + n0 + tx * 4];
    t[r][tx * 4 + 0] = f2bf(v.x);
    t[r][tx * 4 + 1] = f2bf(v.y);
    t[r][tx * 4 + 2] = f2bf(v.z);
    t[r][tx * 4 + 3] = f2bf(v.w);
  }
  __syncthreads();
  int nl = tid >> 2, seg = tid & 3;
  ushort8 o0, o1;
#pragma unroll
  for (int j = 0; j < 8; j++) {
    o0[j] = t[seg * 16 + j][nl];
    o1[j] = t[seg * 16 + 8 + j][nl];
  }
  size_t base = (size_t)(n0 + nl) * 2048 + r0 + seg * 16;
  *(ushort8*)&dst[base] = o0;
  *(ushort8*)&dst[base + 8] = o1;
}

// ---------------------------------------------------------------- gemm0: 256x128x64
// QKV projection. 768 blocks = exactly 3 full occupancy rounds (zero idle CUs,
// vs 384 blocks = 1.5 rounds for the 256x256 tile). 8 waves as 4Mx2N, per-wave
// 64x64, LDS 96KB (2buf x (A 32KB + B 16KB)). 2-phase counted-vmcnt ledger:
// 6 calls/tile (A x4, B-half x2, B granule-permuted so each consumption half
// is dest-linear); phase0 vmcnt(1), phase1 vmcnt(4) (0 only on last tile).
__global__ __launch_bounds__(512) void gemm0n_k(const unsigned short* __restrict__ A,
                                                const unsigned short* __restrict__ Bt,
                                                unsigned short* __restrict__ q_out,
                                                unsigned short* __restrict__ k_out,
                                                unsigned short* __restrict__ v_out) {
  __shared__ __align__(16) unsigned short smem[49152];  // 96 KB

  const int tid = threadIdx.x;
  const int lane = tid & 63, wid = tid >> 6;
  const int wm = wid >> 1, wn = wid & 1;           // 4M x 2N
  const int lr = lane & 15, lq = lane >> 4;
  const int sw = ((lr >> 2) & 1) << 1;

  // XCD-chunked: k8 owns a 4-wide bx stripe; by walks 0..23
  const int k8 = blockIdx.x & 7;
  const int l = blockIdx.x >> 3;                   // 0..95
  const int bx = k8 * 4 + (l & 3);
  const int by = l >> 2;                           // 0..23
  const int row0 = bx * 256, n00 = by * 128;

  const int clog = (tid & 7) ^ (((tid >> 5) & 1) << 1);  // row=tid>>3; ^=(row&4)>>2<<1
  const unsigned short* Asrc = A + (size_t)row0 * 2048 + clog * 8;
  const unsigned short* Bsrc = Bt + (size_t)n00 * 2048 + clog * 8;

  auto stageA = [&](int buf, int k0) {
#pragma unroll
    for (int c = 0; c < 4; c++)
      GLDS16(Asrc + (size_t)(c * 64 + (tid >> 3)) * 2048 + k0,
             &smem[buf * 24576 + c * 4096 + tid * 8]);
  };
  // B phys half h: phys granule pg = h*2 + (tid>>8); logical lg = bitswap(pg)
  auto stageB = [&](int buf, int h, int k0) {
    const int pg = h * 2 + (tid >> 8);
    const int lg = ((pg & 1) << 1) | (pg >> 1);
    const int lrow = lg * 32 + ((tid >> 3) & 31);
    GLDS16(Bsrc + (size_t)lrow * 2048 + k0,
           &smem[buf * 24576 + 16384 + h * 4096 + tid * 8]);
  };

  auto ldA = [&](int buf, int m, int kh) -> bf16x8 {
    const int row = wm * 64 + m * 16 + lr;
    return *(const bf16x8*)&smem[buf * 24576 + row * 64 + (((kh << 2) + lq) ^ sw) * 8];
  };
  auto ldB = [&](int buf, int ni, int kh) -> bf16x8 {
    const int lg = wn * 2 + (ni >> 1);
    const int pg = ((lg & 1) << 1) | (lg >> 1);
    const int prow = pg * 32 + (ni & 1) * 16 + lr;
    return *(const bf16x8*)&smem[buf * 24576 + 16384 + prow * 64 +
                                 (((kh << 2) + lq) ^ sw) * 8];
  };

  f32x4 acc[4][4] = {};

  // prologue: tile 0 — A x4, B-h0, B-h1 (6 calls)
  stageA(0, 0);
  stageB(0, 0, 0);
  stageB(0, 1, 0);

  bf16x8 af[4][2], bfr[4][2];

#pragma unroll 1
  for (int t = 0; t < 32; ++t) {
    const int buf = t & 1, obuf = buf ^ 1;
    const bool nx = (t + 1 < 32);
    const int k0n = (t + 1) << 6;

    // ---- phase 0: all-A + B nh0
    asm volatile("s_waitcnt vmcnt(1)" ::: "memory");  // A x4 + B-h0 done
    asm volatile("s_barrier" ::: "memory");
#pragma unroll
    for (int m = 0; m < 4; m++)
#pragma unroll
      for (int kh = 0; kh < 2; kh++) af[m][kh] = ldA(buf, m, kh);
#pragma unroll
    for (int ni = 0; ni < 2; ni++)
#pragma unroll
      for (int kh = 0; kh < 2; kh++) bfr[ni][kh] = ldB(buf, ni, kh);
    if (nx) stageA(obuf, k0n);
    __builtin_amdgcn_s_setprio(1);
#pragma unroll
    for (int m = 0; m < 4; m++)
#pragma unroll
      for (int ni = 0; ni < 2; ni++)
#pragma unroll
        for (int kh = 0; kh < 2; kh++)
          acc[m][ni] = __builtin_amdgcn_mfma_f32_16x16x32_bf16(af[m][kh], bfr[ni][kh],
                                                               acc[m][ni], 0, 0, 0);
    __builtin_amdgcn_s_setprio(0);

    // ---- phase 1: B nh1
    if (nx) asm volatile("s_waitcnt vmcnt(4)" ::: "memory");  // B-h1 done; 4 next-A fly
    else    asm volatile("s_waitcnt vmcnt(0)" ::: "memory");
    asm volatile("s_barrier" ::: "memory");
#pragma unroll
    for (int ni = 2; ni < 4; ni++)
#pragma unroll
      for (int kh = 0; kh < 2; kh++) bfr[ni][kh] = ldB(buf, ni, kh);
    if (nx) {
      stageB(obuf, 0, k0n);
      stageB(obuf, 1, k0n);
    }
    __builtin_amdgcn_s_setprio(1);
#pragma unroll
    for (int m = 0; m < 4; m++)
#pragma unroll
      for (int ni = 2; ni < 4; ni++)
#pragma unroll
        for (int kh = 0; kh < 2; kh++)
          acc[m][ni] = __builtin_amdgcn_mfma_f32_16x16x32_bf16(af[m][kh], bfr[ni][kh],
                                                               acc[m][ni], 0, 0, 0);
    __builtin_amdgcn_s_setprio(0);
  }

  // epilogue: route Q / K / V^T (register-only; no LDS reuse)
  const int rbase = row0 + wm * 64;
  const int cbase = n00 + wn * 64;
#pragma unroll
  for (int mi = 0; mi < 4; mi++)
#pragma unroll
    for (int ni = 0; ni < 4; ni++)
#pragma unroll
      for (int r = 0; r < 4; r++) {
        int row = rbase + mi * 16 + lq * 4 + r;
        int col = cbase + ni * 16 + lr;
        float v = acc[mi][ni][r];
        if (col < 2048) {
          q_out[(size_t)row * 2048 + col] = f2bf(v);
        } else if (col < 2560) {
          k_out[(size_t)row * 512 + (col - 2048)] = f2bf(v);
        } else {
          int nv = col - 2560;
          int kvh = nv >> 7, d = nv & 127;
          int b = row >> 11, tt = row & 2047;
          v_out[((size_t)(b * NKVH + kvh) * HD + d) * T_SEQ + tt] = f2bf(v);
        }
      }
}

// ---------------------------------------------------------------- GEMM: 256x256x64,
// 4-phase interleave + 2D L2-chunked mapping (round 11, verified) — used for gemm1.
template <int EPI, int NBY, int BYG>
__global__ __launch_bounds__(512) void gemm8_k(const unsigned short* __restrict__ A,
                                               const unsigned short* __restrict__ Bt,
                                               unsigned short* __restrict__ q_out,
                                               unsigned short* __restrict__ k_out,
                                               unsigned short* __restrict__ v_out,
                                               float* __restrict__ f_out) {
  __shared__ __align__(16) unsigned short smem[65536];  // 128 KB

  const int tid = threadIdx.x;
  const int lane = tid & 63, wid = tid >> 6;
  const int wm = wid >> 2, wn = wid & 3;
  const int lr = lane & 15, lq = lane >> 4;
  const int sw = ((lr >> 2) & 1) << 1;

  const int k8 = blockIdx.x & 7;
  const int l = blockIdx.x >> 3;
  const int gi = l / (4 * BYG);
  const int t4 = l % (4 * BYG);
  const int bx = k8 * 4 + (t4 & 3);
  const int by = gi * BYG + (t4 >> 2);
  const int row0 = bx * 256, n00 = by * 256;

  const int clog = (tid & 7) ^ (((tid >> 5) & 1) << 1);
  const unsigned short* Asrc = A + (size_t)row0 * 2048 + clog * 8;
  const unsigned short* Bsrc = Bt + (size_t)n00 * 2048 + clog * 8;

  auto stageA = [&](int buf, int h, int k0) {
#pragma unroll
    for (int c = 0; c < 2; c++) {
      const int rl = c * 128 + h * 64 + (tid >> 3);
      GLDS16(Asrc + (size_t)rl * 2048 + k0,
             &smem[buf * 32768 + (c * 128 + h * 64) * 64 + tid * 8]);
    }
  };
  auto stageB = [&](int buf, int h, int k0) {
#pragma unroll
    for (int c = 0; c < 2; c++) {
      const int pr = h * 128 + c * 64 + (tid >> 3);
      const int p = pr >> 5;
      const int lg = (p < 4) ? (2 * p) : (2 * (p - 4) + 1);
      const int logical = lg * 32 + (pr & 31);
      GLDS16(Bsrc + (size_t)logical * 2048 + k0,
             &smem[buf * 32768 + 16384 + (h * 128 + c * 64) * 64 + tid * 8]);
    }
  };

  auto ldA = [&](int buf, int rl, int kh) -> bf16x8 {
    return *(const bf16x8*)&smem[buf * 32768 + rl * 64 + (((kh << 2) + lq) ^ sw) * 8];
  };
  auto ldB = [&](int buf, int ni, int kh) -> bf16x8 {
    const int p = (ni < 2) ? wn : (4 + wn);
    const int pr = p * 32 + (ni & 1) * 16 + lr;
    return *(const bf16x8*)&smem[buf * 32768 + 16384 + pr * 64 +
                                 (((kh << 2) + lq) ^ sw) * 8];
  };

  f32x4 acc[8][4] = {};

  stageA(0, 0, 0);
  stageB(0, 0, 0);
  stageB(0, 1, 0);
  stageA(0, 1, 0);

  bf16x8 af[4][2], bfr[4][2];

#pragma unroll 1
  for (int t = 0; t < 32; ++t) {
    const int buf = t & 1, obuf = buf ^ 1;
    const bool nx = (t + 1 < 32);
    const int k0n = (t + 1) << 6;

    asm volatile("s_waitcnt vmcnt(4)" ::: "memory");
    asm volatile("s_barrier" ::: "memory");
#pragma unroll
    for (int m = 0; m < 4; m++)
#pragma unroll
      for (int kh = 0; kh < 2; kh++) af[m][kh] = ldA(buf, wm * 128 + m * 16 + lr, kh);
#pragma unroll
    for (int ni = 0; ni < 2; ni++)
#pragma unroll
      for (int kh = 0; kh < 2; kh++) bfr[ni][kh] = ldB(buf, ni, kh);
    if (nx) stageA(obuf, 0, k0n);
    __builtin_amdgcn_s_setprio(1);
#pragma unroll
    for (int m = 0; m < 4; m++)
#pragma unroll
      for (int ni = 0; ni < 2; ni++)
#pragma unroll
        for (int kh = 0; kh < 2; kh++)
          acc[m][ni] = __builtin_amdgcn_mfma_f32_16x16x32_bf16(af[m][kh], bfr[ni][kh],
                                                               acc[m][ni], 0, 0, 0);
    __builtin_amdgcn_s_setprio(0);

    if (nx) asm volatile("s_waitcnt vmcnt(4)" ::: "memory");
    else    asm volatile("s_waitcnt vmcnt(2)" ::: "memory");
    asm volatile("s_barrier" ::: "memory");
#pragma unroll
    for (int ni = 2; ni < 4; ni++)
#pragma unroll
      for (int kh = 0; kh < 2; kh++) bfr[ni][kh] = ldB(buf, ni, kh);
    if (nx) stageB(obuf, 0, k0n);
    __builtin_amdgcn_s_setprio(1);
#pragma unroll
    for (int m = 0; m < 4; m++)
#pragma unroll
      for (int ni = 2; ni < 4; ni++)
#pragma unroll
        for (int kh = 0; kh < 2; kh++)
          acc[m][ni] = __builtin_amdgcn_mfma_f32_16x16x32_bf16(af[m][kh], bfr[ni][kh],
                                                               acc[m][ni], 0, 0, 0);
    __builtin_amdgcn_s_setprio(0);

    if (nx) asm volatile("s_waitcnt vmcnt(4)" ::: "memory");
    else    asm volatile("s_waitcnt vmcnt(0)" ::: "memory");
    asm volatile("s_barrier" ::: "memory");
#pragma unroll
    for (int m = 0; m < 4; m++)
#pragma unroll
      for (int kh = 0; kh < 2; kh++)
        af[m][kh] = ldA(buf, wm * 128 + 64 + m * 16 + lr, kh);
    if (nx) stageB(obuf, 1, k0n);
    __builtin_amdgcn_s_setprio(1);
#pragma unroll
    for (int m = 0; m < 4; m++)
#pragma unroll
      for (int ni = 0; ni < 2; ni++)
#pragma unroll
        for (int kh = 0; kh < 2; kh++)
          acc[4 + m][ni] = __builtin_amdgcn_mfma_f32_16x16x32_bf16(
              af[m][kh], bfr[ni][kh], acc[4 + m][ni], 0, 0, 0);
    __builtin_amdgcn_s_setprio(0);

    asm volatile("s_barrier" ::: "memory");
    if (nx) stageA(obuf, 1, k0n);
    __builtin_amdgcn_s_setprio(1);
#pragma unroll
    for (int m = 0; m < 4; m++)
#pragma unroll
      for (int ni = 2; ni < 4; ni++)
#pragma unroll
        for (int kh = 0; kh < 2; kh++)
          acc[4 + m][ni] = __builtin_amdgcn_mfma_f32_16x16x32_bf16(
              af[m][kh], bfr[ni][kh], acc[4 + m][ni], 0, 0, 0);
    __builtin_amdgcn_s_setprio(0);
  }

  const int rbase = row0 + wm * 128;
  const int cbase = n00 + wn * 64;
#pragma unroll
  for (int mi = 0; mi < 8; mi++)
#pragma unroll
    for (int ni = 0; ni < 4; ni++)
#pragma unroll
      for (int r = 0; r < 4; r++) {
        int row = rbase + mi * 16 + lq * 4 + r;
        int col = cbase + ni * 16 + lr;
        float v = acc[mi][ni][r];
        if (EPI == 0) {
          if (col < 2048) {
            q_out[(size_t)row * 2048 + col] = f2bf(v);
          } else if (col < 2560) {
            k_out[(size_t)row * 512 + (col - 2048)] = f2bf(v);
          } else {
            int nv = col - 2560;
            int kvh = nv >> 7, d = nv & 127;
            int b = row >> 11, tt = row & 2047;
            v_out[((size_t)(b * NKVH + kvh) * HD + d) * T_SEQ + tt] = f2bf(v);
          }
        } else {
          f_out[(size_t)row * 2048 + col] = v;
        }
      }
}

// ---------------------------------------------------------------- RoPE table + K apply
__global__ __launch_bounds__(256) void rope_tab_k(float2* __restrict__ tab) {
  int idx = blockIdx.x * 256 + threadIdx.x;
  int t = idx >> 6, i = idx & 63;
  float theta = exp2f(-(float)i * (13.287712379549449f / 64.0f));
  float s, c;
  sincosf((float)t * theta, &s, &c);
  tab[idx] = make_float2(c, s);
}

// K-only rope (Q rope is folded into attn's Q-fragment load)
__global__ __launch_bounds__(256) void ropek_k(unsigned short* __restrict__ kb,
                                               const float2* __restrict__ tab) {
  int idx = blockIdx.x * 256 + threadIdx.x;
  int i = idx & 63;
  int wi = idx >> 6;
  int kvh = wi & 3;
  int bt = wi >> 2;
  int t = bt & (T_SEQ - 1);
  unsigned short* p = kb + (size_t)bt * 512 + kvh * HD;
  float2 cs = tab[(t << 6) + i];
  float x1 = bf2f(p[i]), x2 = bf2f(p[i + 64]);
  p[i] = f2bf(x1 * cs.x - x2 * cs.y);
  p[i + 64] = f2bf(x1 * cs.y + x2 * cs.x);
}

// ---------------------------------------------------------------- flash attention
// Round-18 verified version (3-slot ring, counted vmcnt, reverse-K,
// defer-rescale, deferred-z softmax, cvt_pk P-pack, shfl_xor exchanges,
// in-register Q-RoPE at fragment load).
__global__ __launch_bounds__(256) void attn_k(const unsigned short* __restrict__ qb,
                                              const unsigned short* __restrict__ kb,
                                              const unsigned short* __restrict__ vt,
                                              const float2* __restrict__ rtab,
                                              unsigned short* __restrict__ ao) {
  __shared__ __align__(16) unsigned short smem[24576];

  const int bid = blockIdx.x;
  const int j = 15 - (bid >> 6);
  const int g = (bid & 7) | (((bid >> 3) & 1) << 3);
  const int hh = (bid >> 4) & 3;
  const int b = g >> 2, kvh = g & 3;
  const int h = kvh * 4 + hh;

  const int tid = threadIdx.x;
  const int wid = tid >> 6, lane = tid & 63;
  const int l31 = lane & 31, lh = lane >> 5;
  const int xr = l31 & 7;
  const float slope2 = exp2f(-0.5f * (float)(h + 1)) * LOG2E;
  const float scale2 = ATT_SCALE * LOG2E;

  const int q0 = j * 128 + wid * 32;
  const int dt_w = j * 4 + wid;
  const int nt = j * 4 + 4;

  const int krow = tid >> 4;
  const int cgk = (tid & 15) ^ (krow & 7);
  const int vr = tid >> 3;
  const int cgv = (tid & 7) ^ (vr & 7);

  const unsigned short* khead = kb + (size_t)(b * T_SEQ) * 512 + kvh * 128;
  const unsigned short* vhead = vt + (size_t)(b * NKVH + kvh) * HD * T_SEQ;

  auto stage = [&](int slot, int tile) {
    const int k0 = tile * 32;
    unsigned short* base = &smem[slot * 8192];
    GLDS16(khead + (size_t)(k0 + krow) * 512 + cgk * 8, base + tid * 8);
    GLDS16(khead + (size_t)(k0 + 16 + krow) * 512 + cgk * 8, base + 2048 + tid * 8);
    GLDS16(vhead + (size_t)(((cgv >> 2) << 6) + vr) * T_SEQ + k0 + (cgv & 3) * 8,
           base + 4096 + tid * 8);
    GLDS16(vhead + (size_t)(((cgv >> 2) << 6) + 32 + vr) * T_SEQ + k0 + (cgv & 3) * 8,
           base + 6144 + tid * 8);
  };

  unsigned short (*ot)[32][136] = (unsigned short(*)[32][136])smem;

  stage(0, nt - 1);
  stage(1, nt - 2);

  const unsigned short* qrow =
      qb + ((size_t)(b * T_SEQ + q0 + l31)) * 2048 + h * HD + lh * 8;
  bf16x8 qf[8];
#pragma unroll
  for (int ds = 0; ds < 8; ds++) qf[ds] = *(const bf16x8*)&qrow[ds * 16];

  {
    const float2* rt = rtab + ((q0 + l31) << 6) + lh * 8;
#pragma unroll
    for (int ds = 0; ds < 4; ds++)
#pragma unroll
      for (int e = 0; e < 8; e++) {
        float2 cs = rt[ds * 16 + e];
        float x1 = bf2f((unsigned short)qf[ds][e]);
        float x2 = bf2f((unsigned short)qf[ds + 4][e]);
        qf[ds][e] = (short)f2bf(x1 * cs.x - x2 * cs.y);
        qf[ds + 4][e] = (short)f2bf(x1 * cs.y + x2 * cs.x);
      }
  }

  f32x16 oacc[4] = {};
  float m2 = -1e30f, l_half = 0.f;
  const float arow = -slope2 * (float)(q0 + l31);

  float cr[16];
#pragma unroll
  for (int r = 0; r < 16; r++) {
    const int crow = (r & 3) + 8 * (r >> 2) + 4 * lh;
    cr[r] = fmaf(slope2, (float)crow, arow);
  }

#pragma unroll 1
  for (int it = 0; it < nt; ++it) {
    const int tt = nt - 1 - it;
    if (it == nt - 1) {
      asm volatile("s_waitcnt vmcnt(0)" ::: "memory");
    } else {
      asm volatile("s_waitcnt vmcnt(4)" ::: "memory");
    }
    asm volatile("s_barrier" ::: "memory");
    if (tt >= 2) stage((it + 2) % 3, tt - 2);

    if (tt <= dt_w) {
      const int slot = it % 3;
      const unsigned short* Kb = &smem[slot * 8192];
      const unsigned short* Vb = &smem[slot * 8192 + 4096];
      const int k0 = tt * 32;

      bf16x8 kf[8];
#pragma unroll
      for (int ds = 0; ds < 8; ds++)
        kf[ds] = *(const bf16x8*)&Kb[l31 * 128 + ((2 * ds + lh) ^ xr) * 8];

      __builtin_amdgcn_s_setprio(1);
      f32x16 sca = 0.f, scb = 0.f;
#pragma unroll
      for (int ds = 0; ds < 4; ds++)
        sca = __builtin_amdgcn_mfma_f32_32x32x16_bf16(kf[ds], qf[ds], sca, 0, 0, 0);
#pragma unroll
      for (int ds = 4; ds < 8; ds++)
        scb = __builtin_amdgcn_mfma_f32_32x32x16_bf16(kf[ds], qf[ds], scb, 0, 0, 0);
      __builtin_amdgcn_s_setprio(0);

      bf16x8 vf[4][2];
#pragma unroll
      for (int dt = 0; dt < 4; dt++)
#pragma unroll
        for (int ks = 0; ks < 2; ks++)
          vf[dt][ks] = *(const bf16x8*)&Vb[((dt & 1) * 32 + l31) * 64 +
                                           (((dt >> 1) * 4 + 2 * ks + lh) ^ xr) * 8];

      float s1[16];
#pragma unroll
      for (int r = 0; r < 16; r++) s1[r] = fmaf(sca[r] + scb[r], scale2, cr[r]);
      if (tt == dt_w) {
#pragma unroll
        for (int r = 0; r < 16; r++) {
          const int crow = (r & 3) + 8 * (r >> 2) + 4 * lh;
          if (crow > l31) s1[r] = -1e30f;
        }
      }

      float z = fmaf(slope2, (float)k0, -m2);

      float t8[8], t4[4];
#pragma unroll
      for (int i = 0; i < 8; i++) t8[i] = fmaxf(s1[i], s1[i + 8]);
#pragma unroll
      for (int i = 0; i < 4; i++) t4[i] = fmaxf(t8[i], t8[i + 4]);
      float mx = fmaxf(fmaxf(t4[0], t4[1]), fmaxf(t4[2], t4[3]));

      float pr[16];
#pragma unroll
      for (int r = 0; r < 16; r++) pr[r] = exp2f(s1[r] + z);

      mx = fmaxf(mx, __shfl_xor(mx, 32));
      if (__any(mx + z > 8.f)) {
        const float mt = (mx + z) + m2;
        const float mnew = fmaxf(m2, mt);
        const float corr = exp2f(m2 - mnew);
        l_half *= corr;
#pragma unroll
        for (int dt = 0; dt < 4; dt++) oacc[dt] *= corr;
        m2 = mnew;
        z = fmaf(slope2, (float)k0, -m2);
#pragma unroll
        for (int r = 0; r < 16; r++) pr[r] = exp2f(s1[r] + z);
      }

      float a8[8], a4[4];
#pragma unroll
      for (int i = 0; i < 8; i++) a8[i] = pr[i] + pr[i + 8];
#pragma unroll
      for (int i = 0; i < 4; i++) a4[i] = a8[i] + a8[i + 4];
      l_half += (a4[0] + a4[1]) + (a4[2] + a4[3]);

      unsigned int w[8];
#pragma unroll
      for (int i = 0; i < 8; i++) w[i] = cvtpk(pr[2 * i], pr[2 * i + 1]);
      const unsigned int ta = __shfl_xor(lh ? w[0] : w[2], 32);
      const unsigned int tb = __shfl_xor(lh ? w[1] : w[3], 32);
      const unsigned int tc = __shfl_xor(lh ? w[4] : w[6], 32);
      const unsigned int td = __shfl_xor(lh ? w[5] : w[7], 32);
      union U4 { unsigned int u[4]; bf16x8 v; } f0, f1;
      f0.u[0] = lh ? ta : w[0];
      f0.u[1] = lh ? tb : w[1];
      f0.u[2] = lh ? w[2] : ta;
      f0.u[3] = lh ? w[3] : tb;
      f1.u[0] = lh ? tc : w[4];
      f1.u[1] = lh ? td : w[5];
      f1.u[2] = lh ? w[6] : tc;
      f1.u[3] = lh ? w[7] : td;

      __builtin_amdgcn_s_setprio(1);
#pragma unroll
      for (int dt = 0; dt < 4; dt++) {
        oacc[dt] =
            __builtin_amdgcn_mfma_f32_32x32x16_bf16(vf[dt][0], f0.v, oacc[dt], 0, 0, 0);
        oacc[dt] =
            __builtin_amdgcn_mfma_f32_32x32x16_bf16(vf[dt][1], f1.v, oacc[dt], 0, 0, 0);
      }
      __builtin_amdgcn_s_setprio(0);
    }
  }

  const float l_tot = l_half + __shfl_xor(l_half, 32);
  const float inv = 1.0f / l_tot;
  __syncthreads();
#pragma unroll
  for (int dt = 0; dt < 4; dt++)
#pragma unroll
    for (int rg = 0; rg < 4; rg++) {
      ushort4v o;
#pragma unroll
      for (int jj = 0; jj < 4; jj++) o[jj] = f2bf(oacc[dt][rg * 4 + jj] * inv);
      *(ushort4v*)&ot[wid][l31][dt * 32 + rg * 8 + lh * 4] = o;
    }
  __syncthreads();
  const int rrow = lane >> 4, chunk = lane & 15;
#pragma unroll
  for (int ps = 0; ps < 8; ps++) {
    const int row = ps * 4 + rrow;
    ushort8 v = *(const ushort8*)&ot[wid][row][chunk * 8];
    *(ushort8*)&ao[((size_t)(b * T_SEQ + q0 + row)) * 2048 + h * HD + chunk * 8] = v;
  }
}

// ---------------------------------------------------------------- launch
extern "C" void kernel_launch(void* const* d_in, const int* in_sizes, int n_in,
                              void* d_out, int out_size, void* d_ws, size_t ws_size,
                              hipStream_t stream) {
  const float* x = (const float*)d_in[0];
  const float* Wq = (const float*)d_in[1];
  const float* Wk = (const float*)d_in[2];
  const float* Wv = (const float*)d_in[3];
  const float* Wo = (const float*)d_in[4];

  char* w = (char*)d_ws;
  unsigned short* xb = (unsigned short*)w;                  // 33.5MB; attn out reuse
  unsigned short* wqt = (unsigned short*)(w + 33554432);    // 12.6MB; Wo^T reuse (first 8.4MB)
  unsigned short* qb = (unsigned short*)(w + 33554432 + 12582912);
  unsigned short* kb = (unsigned short*)(w + 33554432 + 12582912 + 33554432);
  unsigned short* vtb = (unsigned short*)(w + 33554432 + 12582912 + 33554432 + 8388608);
  float2* rtab = (float2*)(w + 33554432 + 8388608);

  castx_k<<<16384, 256, 0, stream>>>(x, xb);
  transqkv_k<<<dim3(48, 32), 256, 0, stream>>>(Wq, Wk, Wv, wqt);
  gemm0n_k<<<768, 512, 0, stream>>>(xb, wqt, qb, kb, vtb);
  rope_tab_k<<<512, 256, 0, stream>>>(rtab);
  ropek_k<<<8192, 256, 0, stream>>>(kb, rtab);
  transw_k<<<dim3(32, 32), 256, 0, stream>>>(Wo, wqt, 2048);
  attn_k<<<1024, 256, 0, stream>>>(qb, kb, vtb, rtab, xb);
  gemm8_k<1, 8, 4><<<256, 512, 0, stream>>>(xb, wqt, nullptr, nullptr, nullptr,
                                            (float*)d_out);
}

// Round 23
// 422.095 us; speedup vs baseline: 1.0633x; 1.0017x over previous
//
#include <hip/hip_runtime.h>
#include <hip/hip_bf16.h>
#include <stdint.h>

// Problem constants
#define T_SEQ 2048
#define DM    2048
#define NH    16
#define NKVH  4
#define HD    128
#define NBATCH 4
#define BT    (NBATCH * T_SEQ)   // 8192 rows of x
#define ATT_SCALE 0.08838834764831845f  // 1/sqrt(128)
#define LOG2E 1.4426950408889634f

typedef __attribute__((ext_vector_type(8))) short bf16x8;
typedef __attribute__((ext_vector_type(4))) float f32x4;
typedef __attribute__((ext_vector_type(16))) float f32x16;
typedef __attribute__((ext_vector_type(8))) unsigned short ushort8;
typedef __attribute__((ext_vector_type(4))) unsigned short ushort4v;

static __device__ __forceinline__ unsigned short f2bf(float f) {
  __hip_bfloat16 h = __float2bfloat16(f);
  return __builtin_bit_cast(unsigned short, h);
}
static __device__ __forceinline__ float bf2f(unsigned short u) {
  unsigned int v = ((unsigned int)u) << 16;
  return __builtin_bit_cast(float, v);
}
static __device__ __forceinline__ unsigned int cvtpk(float a, float b) {
  unsigned int r;
  asm("v_cvt_pk_bf16_f32 %0, %1, %2" : "=v"(r) : "v"(a), "v"(b));
  return r;
}

#define GLDS16(g, l)                                                        \
  __builtin_amdgcn_global_load_lds(                                         \
      (const __attribute__((address_space(1))) void*)(g),                   \
      (__attribute__((address_space(3))) void*)(l), 16, 0, 0)

// ---------------------------------------------------------------- mega1:
// castx (bid<16384) + transqkv (16384..17919). Mutually independent.
__global__ __launch_bounds__(256) void mega1_k(const float* __restrict__ x,
                                               unsigned short* __restrict__ xb,
                                               const float* __restrict__ Wq,
                                               const float* __restrict__ Wk,
                                               const float* __restrict__ Wv,
                                               unsigned short* __restrict__ wqt) {
  __shared__ unsigned short t[64][72];
  const int bid = blockIdx.x;
  const int tid = threadIdx.x;

  if (bid < 16384) {
    int i = (bid * 256 + tid) * 4;
    float4 v = *(const float4*)&x[i];
    ushort4v o;
    o[0] = f2bf(v.x); o[1] = f2bf(v.y); o[2] = f2bf(v.z); o[3] = f2bf(v.w);
    *(ushort4v*)&xb[i] = o;
    return;
  }
  // ---- transqkv
  {
    const int tq = bid - 16384;
    const int bx = tq % 48;
    const int r0 = (tq / 48) * 64;
    const float* src;
    unsigned short* dst;
    int ncols, n0;
    if (bx < 32) {
      src = Wq; dst = wqt; ncols = 2048; n0 = bx * 64;
    } else if (bx < 40) {
      src = Wk; dst = wqt + (size_t)2048 * 2048; ncols = 512; n0 = (bx - 32) * 64;
    } else {
      src = Wv; dst = wqt + (size_t)2560 * 2048; ncols = 512; n0 = (bx - 40) * 64;
    }
    const int tx = tid & 15, ty = tid >> 4;
#pragma unroll
    for (int i = 0; i < 4; i++) {
      int r = ty * 4 + i;
      float4 v = *(const float4*)&src[(size_t)(r0 + r) * ncols + n0 + tx * 4];
      t[r][tx * 4 + 0] = f2bf(v.x);
      t[r][tx * 4 + 1] = f2bf(v.y);
      t[r][tx * 4 + 2] = f2bf(v.z);
      t[r][tx * 4 + 3] = f2bf(v.w);
    }
    __syncthreads();
    int nl = tid >> 2, seg = tid & 3;
    ushort8 o0, o1;
#pragma unroll
    for (int j = 0; j < 8; j++) {
      o0[j] = t[seg * 16 + j][nl];
      o1[j] = t[seg * 16 + 8 + j][nl];
    }
    size_t base = (size_t)(n0 + nl) * 2048 + r0 + seg * 16;
    *(ushort8*)&dst[base] = o0;
    *(ushort8*)&dst[base + 8] = o1;
  }
}

// ---------------------------------------------------------------- mega2:
// ropek w/ direct sincos (bid<8192) + transw Wo (8192..9215) + rope_tab
// (9216..9727). Mutually disjoint: kb / wqt[0..8.4MB] / rtab(=wqt 8.4..9.4MB,
// the old K^T region — free only AFTER gemm0, which this kernel follows).
__global__ __launch_bounds__(256) void mega2_k(unsigned short* __restrict__ kb,
                                               const float* __restrict__ Wo,
                                               unsigned short* __restrict__ wqt,
                                               float2* __restrict__ rtab) {
  __shared__ unsigned short t[64][72];
  const int bid = blockIdx.x;
  const int tid = threadIdx.x;

  if (bid < 8192) {
    // ---- ropek (direct sincos; no table dependency)
    int idx = bid * 256 + tid;
    int i = idx & 63;
    int wi = idx >> 6;
    int kvh = wi & 3;
    int bt = wi >> 2;
    int tt = bt & (T_SEQ - 1);
    unsigned short* p = kb + (size_t)bt * 512 + kvh * HD;
    float theta = exp2f(-(float)i * (13.287712379549449f / 64.0f));
    float s, c;
    sincosf((float)tt * theta, &s, &c);
    float x1 = bf2f(p[i]), x2 = bf2f(p[i + 64]);
    p[i] = f2bf(x1 * c - x2 * s);
    p[i + 64] = f2bf(x1 * s + x2 * c);
    return;
  }
  if (bid < 9216) {
    // ---- transw (Wo, 2048x2048)
    const int tw = bid - 8192;
    const int n0 = (tw & 31) * 64;
    const int r0 = (tw >> 5) * 64;
    const int tx = tid & 15, ty = tid >> 4;
#pragma unroll
    for (int i = 0; i < 4; i++) {
      int r = ty * 4 + i;
      float4 v = *(const float4*)&Wo[(size_t)(r0 + r) * 2048 + n0 + tx * 4];
      t[r][tx * 4 + 0] = f2bf(v.x);
      t[r][tx * 4 + 1] = f2bf(v.y);
      t[r][tx * 4 + 2] = f2bf(v.z);
      t[r][tx * 4 + 3] = f2bf(v.w);
    }
    __syncthreads();
    int nl = tid >> 2, seg = tid & 3;
    ushort8 o0, o1;
#pragma unroll
    for (int j = 0; j < 8; j++) {
      o0[j] = t[seg * 16 + j][nl];
      o1[j] = t[seg * 16 + 8 + j][nl];
    }
    size_t base = (size_t)(n0 + nl) * 2048 + r0 + seg * 16;
    *(ushort8*)&wqt[base] = o0;
    *(ushort8*)&wqt[base + 8] = o1;
    return;
  }
  // ---- rope_tab (for attn's in-register Q-RoPE)
  {
    int idx = (bid - 9216) * 256 + tid;   // 0 .. 131071
    int tt = idx >> 6, i = idx & 63;
    float theta = exp2f(-(float)i * (13.287712379549449f / 64.0f));
    float s, c;
    sincosf((float)tt * theta, &s, &c);
    rtab[idx] = make_float2(c, s);
  }
}

// ---------------------------------------------------------------- gemm0: 256x128x64
// (round-21 verified: 768 blocks = 3 exact rounds; 2-phase counted-vmcnt)
__global__ __launch_bounds__(512) void gemm0n_k(const unsigned short* __restrict__ A,
                                                const unsigned short* __restrict__ Bt,
                                                unsigned short* __restrict__ q_out,
                                                unsigned short* __restrict__ k_out,
                                                unsigned short* __restrict__ v_out) {
  __shared__ __align__(16) unsigned short smem[49152];  // 96 KB

  const int tid = threadIdx.x;
  const int lane = tid & 63, wid = tid >> 6;
  const int wm = wid >> 1, wn = wid & 1;
  const int lr = lane & 15, lq = lane >> 4;
  const int sw = ((lr >> 2) & 1) << 1;

  const int k8 = blockIdx.x & 7;
  const int l = blockIdx.x >> 3;
  const int bx = k8 * 4 + (l & 3);
  const int by = l >> 2;
  const int row0 = bx * 256, n00 = by * 128;

  const int clog = (tid & 7) ^ (((tid >> 5) & 1) << 1);
  const unsigned short* Asrc = A + (size_t)row0 * 2048 + clog * 8;
  const unsigned short* Bsrc = Bt + (size_t)n00 * 2048 + clog * 8;

  auto stageA = [&](int buf, int k0) {
#pragma unroll
    for (int c = 0; c < 4; c++)
      GLDS16(Asrc + (size_t)(c * 64 + (tid >> 3)) * 2048 + k0,
             &smem[buf * 24576 + c * 4096 + tid * 8]);
  };
  auto stageB = [&](int buf, int h, int k0) {
    const int pg = h * 2 + (tid >> 8);
    const int lg = ((pg & 1) << 1) | (pg >> 1);
    const int lrow = lg * 32 + ((tid >> 3) & 31);
    GLDS16(Bsrc + (size_t)lrow * 2048 + k0,
           &smem[buf * 24576 + 16384 + h * 4096 + tid * 8]);
  };

  auto ldA = [&](int buf, int m, int kh) -> bf16x8 {
    const int row = wm * 64 + m * 16 + lr;
    return *(const bf16x8*)&smem[buf * 24576 + row * 64 + (((kh << 2) + lq) ^ sw) * 8];
  };
  auto ldB = [&](int buf, int ni, int kh) -> bf16x8 {
    const int lg = wn * 2 + (ni >> 1);
    const int pg = ((lg & 1) << 1) | (lg >> 1);
    const int prow = pg * 32 + (ni & 1) * 16 + lr;
    return *(const bf16x8*)&smem[buf * 24576 + 16384 + prow * 64 +
                                 (((kh << 2) + lq) ^ sw) * 8];
  };

  f32x4 acc[4][4] = {};

  stageA(0, 0);
  stageB(0, 0, 0);
  stageB(0, 1, 0);

  bf16x8 af[4][2], bfr[4][2];

#pragma unroll 1
  for (int t = 0; t < 32; ++t) {
    const int buf = t & 1, obuf = buf ^ 1;
    const bool nx = (t + 1 < 32);
    const int k0n = (t + 1) << 6;

    asm volatile("s_waitcnt vmcnt(1)" ::: "memory");
    asm volatile("s_barrier" ::: "memory");
#pragma unroll
    for (int m = 0; m < 4; m++)
#pragma unroll
      for (int kh = 0; kh < 2; kh++) af[m][kh] = ldA(buf, m, kh);
#pragma unroll
    for (int ni = 0; ni < 2; ni++)
#pragma unroll
      for (int kh = 0; kh < 2; kh++) bfr[ni][kh] = ldB(buf, ni, kh);
    if (nx) stageA(obuf, k0n);
    __builtin_amdgcn_s_setprio(1);
#pragma unroll
    for (int m = 0; m < 4; m++)
#pragma unroll
      for (int ni = 0; ni < 2; ni++)
#pragma unroll
        for (int kh = 0; kh < 2; kh++)
          acc[m][ni] = __builtin_amdgcn_mfma_f32_16x16x32_bf16(af[m][kh], bfr[ni][kh],
                                                               acc[m][ni], 0, 0, 0);
    __builtin_amdgcn_s_setprio(0);

    if (nx) asm volatile("s_waitcnt vmcnt(4)" ::: "memory");
    else    asm volatile("s_waitcnt vmcnt(0)" ::: "memory");
    asm volatile("s_barrier" ::: "memory");
#pragma unroll
    for (int ni = 2; ni < 4; ni++)
#pragma unroll
      for (int kh = 0; kh < 2; kh++) bfr[ni][kh] = ldB(buf, ni, kh);
    if (nx) {
      stageB(obuf, 0, k0n);
      stageB(obuf, 1, k0n);
    }
    __builtin_amdgcn_s_setprio(1);
#pragma unroll
    for (int m = 0; m < 4; m++)
#pragma unroll
      for (int ni = 2; ni < 4; ni++)
#pragma unroll
        for (int kh = 0; kh < 2; kh++)
          acc[m][ni] = __builtin_amdgcn_mfma_f32_16x16x32_bf16(af[m][kh], bfr[ni][kh],
                                                               acc[m][ni], 0, 0, 0);
    __builtin_amdgcn_s_setprio(0);
  }

  const int rbase = row0 + wm * 64;
  const int cbase = n00 + wn * 64;
#pragma unroll
  for (int mi = 0; mi < 4; mi++)
#pragma unroll
    for (int ni = 0; ni < 4; ni++)
#pragma unroll
      for (int r = 0; r < 4; r++) {
        int row = rbase + mi * 16 + lq * 4 + r;
        int col = cbase + ni * 16 + lr;
        float v = acc[mi][ni][r];
        if (col < 2048) {
          q_out[(size_t)row * 2048 + col] = f2bf(v);
        } else if (col < 2560) {
          k_out[(size_t)row * 512 + (col - 2048)] = f2bf(v);
        } else {
          int nv = col - 2560;
          int kvh = nv >> 7, d = nv & 127;
          int b = row >> 11, tt = row & 2047;
          v_out[((size_t)(b * NKVH + kvh) * HD + d) * T_SEQ + tt] = f2bf(v);
        }
      }
}

// ---------------------------------------------------------------- gemm1: 256x256x64
// (round-11 verified 4-phase + L2-chunked mapping)
template <int EPI, int NBY, int BYG>
__global__ __launch_bounds__(512) void gemm8_k(const unsigned short* __restrict__ A,
                                               const unsigned short* __restrict__ Bt,
                                               unsigned short* __restrict__ q_out,
                                               unsigned short* __restrict__ k_out,
                                               unsigned short* __restrict__ v_out,
                                               float* __restrict__ f_out) {
  __shared__ __align__(16) unsigned short smem[65536];  // 128 KB

  const int tid = threadIdx.x;
  const int lane = tid & 63, wid = tid >> 6;
  const int wm = wid >> 2, wn = wid & 3;
  const int lr = lane & 15, lq = lane >> 4;
  const int sw = ((lr >> 2) & 1) << 1;

  const int k8 = blockIdx.x & 7;
  const int l = blockIdx.x >> 3;
  const int gi = l / (4 * BYG);
  const int t4 = l % (4 * BYG);
  const int bx = k8 * 4 + (t4 & 3);
  const int by = gi * BYG + (t4 >> 2);
  const int row0 = bx * 256, n00 = by * 256;

  const int clog = (tid & 7) ^ (((tid >> 5) & 1) << 1);
  const unsigned short* Asrc = A + (size_t)row0 * 2048 + clog * 8;
  const unsigned short* Bsrc = Bt + (size_t)n00 * 2048 + clog * 8;

  auto stageA = [&](int buf, int h, int k0) {
#pragma unroll
    for (int c = 0; c < 2; c++) {
      const int rl = c * 128 + h * 64 + (tid >> 3);
      GLDS16(Asrc + (size_t)rl * 2048 + k0,
             &smem[buf * 32768 + (c * 128 + h * 64) * 64 + tid * 8]);
    }
  };
  auto stageB = [&](int buf, int h, int k0) {
#pragma unroll
    for (int c = 0; c < 2; c++) {
      const int pr = h * 128 + c * 64 + (tid >> 3);
      const int p = pr >> 5;
      const int lg = (p < 4) ? (2 * p) : (2 * (p - 4) + 1);
      const int logical = lg * 32 + (pr & 31);
      GLDS16(Bsrc + (size_t)logical * 2048 + k0,
             &smem[buf * 32768 + 16384 + (h * 128 + c * 64) * 64 + tid * 8]);
    }
  };

  auto ldA = [&](int buf, int rl, int kh) -> bf16x8 {
    return *(const bf16x8*)&smem[buf * 32768 + rl * 64 + (((kh << 2) + lq) ^ sw) * 8];
  };
  auto ldB = [&](int buf, int ni, int kh) -> bf16x8 {
    const int p = (ni < 2) ? wn : (4 + wn);
    const int pr = p * 32 + (ni & 1) * 16 + lr;
    return *(const bf16x8*)&smem[buf * 32768 + 16384 + pr * 64 +
                                 (((kh << 2) + lq) ^ sw) * 8];
  };

  f32x4 acc[8][4] = {};

  stageA(0, 0, 0);
  stageB(0, 0, 0);
  stageB(0, 1, 0);
  stageA(0, 1, 0);

  bf16x8 af[4][2], bfr[4][2];

#pragma unroll 1
  for (int t = 0; t < 32; ++t) {
    const int buf = t & 1, obuf = buf ^ 1;
    const bool nx = (t + 1 < 32);
    const int k0n = (t + 1) << 6;

    asm volatile("s_waitcnt vmcnt(4)" ::: "memory");
    asm volatile("s_barrier" ::: "memory");
#pragma unroll
    for (int m = 0; m < 4; m++)
#pragma unroll
      for (int kh = 0; kh < 2; kh++) af[m][kh] = ldA(buf, wm * 128 + m * 16 + lr, kh);
#pragma unroll
    for (int ni = 0; ni < 2; ni++)
#pragma unroll
      for (int kh = 0; kh < 2; kh++) bfr[ni][kh] = ldB(buf, ni, kh);
    if (nx) stageA(obuf, 0, k0n);
    __builtin_amdgcn_s_setprio(1);
#pragma unroll
    for (int m = 0; m < 4; m++)
#pragma unroll
      for (int ni = 0; ni < 2; ni++)
#pragma unroll
        for (int kh = 0; kh < 2; kh++)
          acc[m][ni] = __builtin_amdgcn_mfma_f32_16x16x32_bf16(af[m][kh], bfr[ni][kh],
                                                               acc[m][ni], 0, 0, 0);
    __builtin_amdgcn_s_setprio(0);

    if (nx) asm volatile("s_waitcnt vmcnt(4)" ::: "memory");
    else    asm volatile("s_waitcnt vmcnt(2)" ::: "memory");
    asm volatile("s_barrier" ::: "memory");
#pragma unroll
    for (int ni = 2; ni < 4; ni++)
#pragma unroll
      for (int kh = 0; kh < 2; kh++) bfr[ni][kh] = ldB(buf, ni, kh);
    if (nx) stageB(obuf, 0, k0n);
    __builtin_amdgcn_s_setprio(1);
#pragma unroll
    for (int m = 0; m < 4; m++)
#pragma unroll
      for (int ni = 2; ni < 4; ni++)
#pragma unroll
        for (int kh = 0; kh < 2; kh++)
          acc[m][ni] = __builtin_amdgcn_mfma_f32_16x16x32_bf16(af[m][kh], bfr[ni][kh],
                                                               acc[m][ni], 0, 0, 0);
    __builtin_amdgcn_s_setprio(0);

    if (nx) asm volatile("s_waitcnt vmcnt(4)" ::: "memory");
    else    asm volatile("s_waitcnt vmcnt(0)" ::: "memory");
    asm volatile("s_barrier" ::: "memory");
#pragma unroll
    for (int m = 0; m < 4; m++)
#pragma unroll
      for (int kh = 0; kh < 2; kh++)
        af[m][kh] = ldA(buf, wm * 128 + 64 + m * 16 + lr, kh);
    if (nx) stageB(obuf, 1, k0n);
    __builtin_amdgcn_s_setprio(1);
#pragma unroll
    for (int m = 0; m < 4; m++)
#pragma unroll
      for (int ni = 0; ni < 2; ni++)
#pragma unroll
        for (int kh = 0; kh < 2; kh++)
          acc[4 + m][ni] = __builtin_amdgcn_mfma_f32_16x16x32_bf16(
              af[m][kh], bfr[ni][kh], acc[4 + m][ni], 0, 0, 0);
    __builtin_amdgcn_s_setprio(0);

    asm volatile("s_barrier" ::: "memory");
    if (nx) stageA(obuf, 1, k0n);
    __builtin_amdgcn_s_setprio(1);
#pragma unroll
    for (int m = 0; m < 4; m++)
#pragma unroll
      for (int ni = 2; ni < 4; ni++)
#pragma unroll
        for (int kh = 0; kh < 2; kh++)
          acc[4 + m][ni] = __builtin_amdgcn_mfma_f32_16x16x32_bf16(
              af[m][kh], bfr[ni][kh], acc[4 + m][ni], 0, 0, 0);
    __builtin_amdgcn_s_setprio(0);
  }

  const int rbase = row0 + wm * 128;
  const int cbase = n00 + wn * 64;
#pragma unroll
  for (int mi = 0; mi < 8; mi++)
#pragma unroll
    for (int ni = 0; ni < 4; ni++)
#pragma unroll
      for (int r = 0; r < 4; r++) {
        int row = rbase + mi * 16 + lq * 4 + r;
        int col = cbase + ni * 16 + lr;
        float v = acc[mi][ni][r];
        if (EPI == 0) {
          if (col < 2048) {
            q_out[(size_t)row * 2048 + col] = f2bf(v);
          } else if (col < 2560) {
            k_out[(size_t)row * 512 + (col - 2048)] = f2bf(v);
          } else {
            int nv = col - 2560;
            int kvh = nv >> 7, d = nv & 127;
            int b = row >> 11, tt = row & 2047;
            v_out[((size_t)(b * NKVH + kvh) * HD + d) * T_SEQ + tt] = f2bf(v);
          }
        } else {
          f_out[(size_t)row * 2048 + col] = v;
        }
      }
}

// ---------------------------------------------------------------- flash attention
// (round-18/21 verified: 3-slot ring, counted vmcnt, reverse-K, defer-rescale,
// deferred-z softmax, cvt_pk, shfl_xor exchanges, in-register Q-RoPE)
__global__ __launch_bounds__(256) void attn_k(const unsigned short* __restrict__ qb,
                                              const unsigned short* __restrict__ kb,
                                              const unsigned short* __restrict__ vt,
                                              const float2* __restrict__ rtab,
                                              unsigned short* __restrict__ ao) {
  __shared__ __align__(16) unsigned short smem[24576];

  const int bid = blockIdx.x;
  const int j = 15 - (bid >> 6);
  const int g = (bid & 7) | (((bid >> 3) & 1) << 3);
  const int hh = (bid >> 4) & 3;
  const int b = g >> 2, kvh = g & 3;
  const int h = kvh * 4 + hh;

  const int tid = threadIdx.x;
  const int wid = tid >> 6, lane = tid & 63;
  const int l31 = lane & 31, lh = lane >> 5;
  const int xr = l31 & 7;
  const float slope2 = exp2f(-0.5f * (float)(h + 1)) * LOG2E;
  const float scale2 = ATT_SCALE * LOG2E;

  const int q0 = j * 128 + wid * 32;
  const int dt_w = j * 4 + wid;
  const int nt = j * 4 + 4;

  const int krow = tid >> 4;
  const int cgk = (tid & 15) ^ (krow & 7);
  const int vr = tid >> 3;
  const int cgv = (tid & 7) ^ (vr & 7);

  const unsigned short* khead = kb + (size_t)(b * T_SEQ) * 512 + kvh * 128;
  const unsigned short* vhead = vt + (size_t)(b * NKVH + kvh) * HD * T_SEQ;

  auto stage = [&](int slot, int tile) {
    const int k0 = tile * 32;
    unsigned short* base = &smem[slot * 8192];
    GLDS16(khead + (size_t)(k0 + krow) * 512 + cgk * 8, base + tid * 8);
    GLDS16(khead + (size_t)(k0 + 16 + krow) * 512 + cgk * 8, base + 2048 + tid * 8);
    GLDS16(vhead + (size_t)(((cgv >> 2) << 6) + vr) * T_SEQ + k0 + (cgv & 3) * 8,
           base + 4096 + tid * 8);
    GLDS16(vhead + (size_t)(((cgv >> 2) << 6) + 32 + vr) * T_SEQ + k0 + (cgv & 3) * 8,
           base + 6144 + tid * 8);
  };

  unsigned short (*ot)[32][136] = (unsigned short(*)[32][136])smem;

  stage(0, nt - 1);
  stage(1, nt - 2);

  const unsigned short* qrow =
      qb + ((size_t)(b * T_SEQ + q0 + l31)) * 2048 + h * HD + lh * 8;
  bf16x8 qf[8];
#pragma unroll
  for (int ds = 0; ds < 8; ds++) qf[ds] = *(const bf16x8*)&qrow[ds * 16];

  {
    const float2* rt = rtab + ((q0 + l31) << 6) + lh * 8;
#pragma unroll
    for (int ds = 0; ds < 4; ds++)
#pragma unroll
      for (int e = 0; e < 8; e++) {
        float2 cs = rt[ds * 16 + e];
        float x1 = bf2f((unsigned short)qf[ds][e]);
        float x2 = bf2f((unsigned short)qf[ds + 4][e]);
        qf[ds][e] = (short)f2bf(x1 * cs.x - x2 * cs.y);
        qf[ds + 4][e] = (short)f2bf(x1 * cs.y + x2 * cs.x);
      }
  }

  f32x16 oacc[4] = {};
  float m2 = -1e30f, l_half = 0.f;
  const float arow = -slope2 * (float)(q0 + l31);

  float cr[16];
#pragma unroll
  for (int r = 0; r < 16; r++) {
    const int crow = (r & 3) + 8 * (r >> 2) + 4 * lh;
    cr[r] = fmaf(slope2, (float)crow, arow);
  }

#pragma unroll 1
  for (int it = 0; it < nt; ++it) {
    const int tt = nt - 1 - it;
    if (it == nt - 1) {
      asm volatile("s_waitcnt vmcnt(0)" ::: "memory");
    } else {
      asm volatile("s_waitcnt vmcnt(4)" ::: "memory");
    }
    asm volatile("s_barrier" ::: "memory");
    if (tt >= 2) stage((it + 2) % 3, tt - 2);

    if (tt <= dt_w) {
      const int slot = it % 3;
      const unsigned short* Kb = &smem[slot * 8192];
      const unsigned short* Vb = &smem[slot * 8192 + 4096];
      const int k0 = tt * 32;

      bf16x8 kf[8];
#pragma unroll
      for (int ds = 0; ds < 8; ds++)
        kf[ds] = *(const bf16x8*)&Kb[l31 * 128 + ((2 * ds + lh) ^ xr) * 8];

      __builtin_amdgcn_s_setprio(1);
      f32x16 sca = 0.f, scb = 0.f;
#pragma unroll
      for (int ds = 0; ds < 4; ds++)
        sca = __builtin_amdgcn_mfma_f32_32x32x16_bf16(kf[ds], qf[ds], sca, 0, 0, 0);
#pragma unroll
      for (int ds = 4; ds < 8; ds++)
        scb = __builtin_amdgcn_mfma_f32_32x32x16_bf16(kf[ds], qf[ds], scb, 0, 0, 0);
      __builtin_amdgcn_s_setprio(0);

      bf16x8 vf[4][2];
#pragma unroll
      for (int dt = 0; dt < 4; dt++)
#pragma unroll
        for (int ks = 0; ks < 2; ks++)
          vf[dt][ks] = *(const bf16x8*)&Vb[((dt & 1) * 32 + l31) * 64 +
                                           (((dt >> 1) * 4 + 2 * ks + lh) ^ xr) * 8];

      float s1[16];
#pragma unroll
      for (int r = 0; r < 16; r++) s1[r] = fmaf(sca[r] + scb[r], scale2, cr[r]);
      if (tt == dt_w) {
#pragma unroll
        for (int r = 0; r < 16; r++) {
          const int crow = (r & 3) + 8 * (r >> 2) + 4 * lh;
          if (crow > l31) s1[r] = -1e30f;
        }
      }

      float z = fmaf(slope2, (float)k0, -m2);

      float t8[8], t4[4];
#pragma unroll
      for (int i = 0; i < 8; i++) t8[i] = fmaxf(s1[i], s1[i + 8]);
#pragma unroll
      for (int i = 0; i < 4; i++) t4[i] = fmaxf(t8[i], t8[i + 4]);
      float mx = fmaxf(fmaxf(t4[0], t4[1]), fmaxf(t4[2], t4[3]));

      float pr[16];
#pragma unroll
      for (int r = 0; r < 16; r++) pr[r] = exp2f(s1[r] + z);

      mx = fmaxf(mx, __shfl_xor(mx, 32));
      if (__any(mx + z > 8.f)) {
        const float mt = (mx + z) + m2;
        const float mnew = fmaxf(m2, mt);
        const float corr = exp2f(m2 - mnew);
        l_half *= corr;
#pragma unroll
        for (int dt = 0; dt < 4; dt++) oacc[dt] *= corr;
        m2 = mnew;
        z = fmaf(slope2, (float)k0, -m2);
#pragma unroll
        for (int r = 0; r < 16; r++) pr[r] = exp2f(s1[r] + z);
      }

      float a8[8], a4[4];
#pragma unroll
      for (int i = 0; i < 8; i++) a8[i] = pr[i] + pr[i + 8];
#pragma unroll
      for (int i = 0; i < 4; i++) a4[i] = a8[i] + a8[i + 4];
      l_half += (a4[0] + a4[1]) + (a4[2] + a4[3]);

      unsigned int w[8];
#pragma unroll
      for (int i = 0; i < 8; i++) w[i] = cvtpk(pr[2 * i], pr[2 * i + 1]);
      const unsigned int ta = __shfl_xor(lh ? w[0] : w[2], 32);
      const unsigned int tb = __shfl_xor(lh ? w[1] : w[3], 32);
      const unsigned int tc = __shfl_xor(lh ? w[4] : w[6], 32);
      const unsigned int td = __shfl_xor(lh ? w[5] : w[7], 32);
      union U4 { unsigned int u[4]; bf16x8 v; } f0, f1;
      f0.u[0] = lh ? ta : w[0];
      f0.u[1] = lh ? tb : w[1];
      f0.u[2] = lh ? w[2] : ta;
      f0.u[3] = lh ? w[3] : tb;
      f1.u[0] = lh ? tc : w[4];
      f1.u[1] = lh ? td : w[5];
      f1.u[2] = lh ? w[6] : tc;
      f1.u[3] = lh ? w[7] : td;

      __builtin_amdgcn_s_setprio(1);
#pragma unroll
      for (int dt = 0; dt < 4; dt++) {
        oacc[dt] =
            __builtin_amdgcn_mfma_f32_32x32x16_bf16(vf[dt][0], f0.v, oacc[dt], 0, 0, 0);
        oacc[dt] =
            __builtin_amdgcn_mfma_f32_32x32x16_bf16(vf[dt][1], f1.v, oacc[dt], 0, 0, 0);
      }
      __builtin_amdgcn_s_setprio(0);
    }
  }

  const float l_tot = l_half + __shfl_xor(l_half, 32);
  const float inv = 1.0f / l_tot;
  __syncthreads();
#pragma unroll
  for (int dt = 0; dt < 4; dt++)
#pragma unroll
    for (int rg = 0; rg < 4; rg++) {
      ushort4v o;
#pragma unroll
      for (int jj = 0; jj < 4; jj++) o[jj] = f2bf(oacc[dt][rg * 4 + jj] * inv);
      *(ushort4v*)&ot[wid][l31][dt * 32 + rg * 8 + lh * 4] = o;
    }
  __syncthreads();
  const int rrow = lane >> 4, chunk = lane & 15;
#pragma unroll
  for (int ps = 0; ps < 8; ps++) {
    const int row = ps * 4 + rrow;
    ushort8 v = *(const ushort8*)&ot[wid][row][chunk * 8];
    *(ushort8*)&ao[((size_t)(b * T_SEQ + q0 + row)) * 2048 + h * HD + chunk * 8] = v;
  }
}

// ---------------------------------------------------------------- launch
extern "C" void kernel_launch(void* const* d_in, const int* in_sizes, int n_in,
                              void* d_out, int out_size, void* d_ws, size_t ws_size,
                              hipStream_t stream) {
  const float* x = (const float*)d_in[0];
  const float* Wq = (const float*)d_in[1];
  const float* Wk = (const float*)d_in[2];
  const float* Wv = (const float*)d_in[3];
  const float* Wo = (const float*)d_in[4];

  char* w = (char*)d_ws;
  unsigned short* xb = (unsigned short*)w;                  // 33.5MB; attn out reuse
  unsigned short* wqt = (unsigned short*)(w + 33554432);    // 12.6MB; Wo^T reuse (first 8.4MB)
  unsigned short* qb = (unsigned short*)(w + 33554432 + 12582912);
  unsigned short* kb = (unsigned short*)(w + 33554432 + 12582912 + 33554432);
  unsigned short* vtb = (unsigned short*)(w + 33554432 + 12582912 + 33554432 + 8388608);
  // rtab aliases the K^T weight region (wqt bytes 8.4..9.4MB) — written only in
  // mega2, i.e. strictly AFTER gemm0 consumed K^T.
  float2* rtab = (float2*)(w + 33554432 + 8388608);

  mega1_k<<<17920, 256, 0, stream>>>(x, xb, Wq, Wk, Wv, wqt);
  gemm0n_k<<<768, 512, 0, stream>>>(xb, wqt, qb, kb, vtb);
  mega2_k<<<9728, 256, 0, stream>>>(kb, Wo, wqt, rtab);
  attn_k<<<1024, 256, 0, stream>>>(qb, kb, vtb, rtab, xb);
  gemm8_k<1, 8, 4><<<256, 512, 0, stream>>>(xb, wqt, nullptr, nullptr, nullptr,
                                            (float*)d_out);
}